// Round 8
// baseline (189.668 us; speedup 1.0000x reference)
//
#include <hip/hip_runtime.h>
#include <hip/hip_bf16.h>

#define T_SEQ 2048
#define NB 4
#define NH 16
#define DK 64
#define DM 1024

typedef __attribute__((ext_vector_type(8))) __bf16 bf16x8;
typedef __attribute__((ext_vector_type(4))) __bf16 bf16x4;
typedef __attribute__((ext_vector_type(4))) float f32x4;
typedef __attribute__((ext_vector_type(2))) int i32x2;
typedef __attribute__((ext_vector_type(4))) int i32x4;

// async global->LDS, 16B per lane, wave-uniform LDS base + lane*16
__device__ __forceinline__ void gl_lds16(const __bf16* g, __bf16* l) {
  __builtin_amdgcn_global_load_lds(
      (const __attribute__((address_space(1))) void*)g,
      (__attribute__((address_space(3))) void*)l,
      16, 0, 0);
}

__device__ __forceinline__ unsigned cvt_pk_bf16(float lo, float hi) {
  unsigned r;
  asm("v_cvt_pk_bf16_f32 %0, %1, %2" : "=v"(r) : "v"(lo), "v"(hi));
  return r;
}

// ---------------- cast fp32 -> bf16, vectorized ----------------
__global__ __launch_bounds__(256) void cast_f32_to_bf16(const float* __restrict__ in,
                                                        __bf16* __restrict__ out, int n4) {
  int i = blockIdx.x * 256 + threadIdx.x;
  if (i >= n4) return;
  float4 v = reinterpret_cast<const float4*>(in)[i];
  bf16x4 o;
  o[0] = (__bf16)v.x; o[1] = (__bf16)v.y; o[2] = (__bf16)v.z; o[3] = (__bf16)v.w;
  reinterpret_cast<bf16x4*>(out)[i] = o;
}

// fused cast of the four weight matrices (each DM*DM fp32)
__global__ __launch_bounds__(256) void cast_weights(const float* __restrict__ a,
                                                    const float* __restrict__ b,
                                                    const float* __restrict__ c,
                                                    const float* __restrict__ d,
                                                    __bf16* __restrict__ oa,
                                                    __bf16* __restrict__ ob,
                                                    __bf16* __restrict__ oc,
                                                    __bf16* __restrict__ od) {
  const int which = blockIdx.y;
  const float* in = (which == 0) ? a : (which == 1) ? b : (which == 2) ? c : d;
  __bf16* out = (which == 0) ? oa : (which == 1) ? ob : (which == 2) ? oc : od;
  int i = blockIdx.x * 256 + threadIdx.x;
  float4 v = reinterpret_cast<const float4*>(in)[i];
  bf16x4 o;
  o[0] = (__bf16)v.x; o[1] = (__bf16)v.y; o[2] = (__bf16)v.z; o[3] = (__bf16)v.w;
  reinterpret_cast<bf16x4*>(out)[i] = o;
}

// ---------------- NT GEMM (m97-style): C[M,N] = A[M,K] * B[N,K]^T ---------
template<typename CT, bool SCALE>
__global__ __launch_bounds__(256, 2) void gemm_nt(const __bf16* __restrict__ A,
                                                  const __bf16* __restrict__ B,
                                                  CT* __restrict__ C,
                                                  int M, int N, int K) {
  __shared__ alignas(16) __bf16 As[128][64];
  __shared__ alignas(16) __bf16 Bs[128][64];
  const int tid = threadIdx.x;
  const int m0 = blockIdx.y * 128, n0 = blockIdx.x * 128;
  const int w = tid >> 6, l = tid & 63, lg = l >> 4, lr = l & 15;
  const int wr = (w >> 1) * 64, wc = (w & 1) * 64;
  const int srow = l >> 3;              // 0..7 within 8-row segment
  const int schunk = (l & 7) ^ srow;    // inverse-swizzled source 16B chunk

  f32x4 acc[4][4] = {};
  const int rsw = lr & 7;

  for (int k0 = 0; k0 < K; k0 += 64) {
    __syncthreads();
    #pragma unroll
    for (int j = 0; j < 4; ++j) {
      const int rbase = (w * 4 + j) * 8;
      gl_lds16(A + (size_t)(m0 + rbase + srow) * K + k0 + schunk * 8, &As[rbase][0]);
      gl_lds16(B + (size_t)(n0 + rbase + srow) * K + k0 + schunk * 8, &Bs[rbase][0]);
    }
    asm volatile("s_waitcnt vmcnt(0)" ::: "memory");
    __syncthreads();
    #pragma unroll
    for (int kk = 0; kk < 2; ++kk) {
      bf16x8 af[4], bfr[4];
      #pragma unroll
      for (int mt = 0; mt < 4; ++mt) {
        const char* p = (const char*)&As[wr + mt * 16 + lr][0];
        af[mt] = *reinterpret_cast<const bf16x8*>(p + (((kk * 4 + lg) ^ rsw) << 4));
      }
      #pragma unroll
      for (int nt = 0; nt < 4; ++nt) {
        const char* p = (const char*)&Bs[wc + nt * 16 + lr][0];
        bfr[nt] = *reinterpret_cast<const bf16x8*>(p + (((kk * 4 + lg) ^ rsw) << 4));
      }
      __builtin_amdgcn_s_setprio(1);
      #pragma unroll
      for (int mt = 0; mt < 4; ++mt)
        #pragma unroll
        for (int nt = 0; nt < 4; ++nt)
          acc[mt][nt] = __builtin_amdgcn_mfma_f32_16x16x32_bf16(af[mt], bfr[nt], acc[mt][nt], 0, 0, 0);
      __builtin_amdgcn_s_setprio(0);
    }
  }
  #pragma unroll
  for (int mt = 0; mt < 4; ++mt)
    #pragma unroll
    for (int nt = 0; nt < 4; ++nt)
      #pragma unroll
      for (int r = 0; r < 4; ++r) {
        const int mg = m0 + wr + mt * 16 + 4 * lg + r;
        const int ng = n0 + wc + nt * 16 + lr;
        float v = acc[mt][nt][r];
        if (SCALE) v *= 0.18033688f;  // 0.125 * log2(e): folds attn scale+exp2 base
        C[(size_t)mg * N + ng] = (CT)v;
      }
}

// ---------------- causal flash attention ----------------------------------
// grid: 1024 blocks; XCD remap: bh = (f&7)*8|(f>>3)&7, qpair = f>>6.
// MERGED dual-chunk; no-max softmax (P = 2^S, f32-safe); SWAPPED QK^T:
// S^T = mfma(K,Q) leaves each lane holding q=lr, keys 16ct+4lg+r. With the
// k-slot permutation pi(8lg+j) = {4lg+j, 16+4lg+(j-4)}, the post-QK register
// contents ARE the PV A-fragment after v_cvt_pk_bf16_f32 -- no LDS roundtrip,
// no cross-lane ops. V read per-lane as 4x ds_read_b64 at pi offsets.
__global__ __launch_bounds__(256, 3) void attn_fwd(const __bf16* __restrict__ Q,
                                                   const __bf16* __restrict__ K,
                                                   const __bf16* __restrict__ VT,
                                                   __bf16* __restrict__ AO) {
  __shared__ alignas(16) __bf16 Ks[2][64][64];
  __shared__ alignas(16) __bf16 Vs[2][64][64];  // Vs[d][key] (V^T tile)
  const int tid = threadIdx.x;
  const int w = tid >> 6, l = tid & 63, lg = l >> 4, lr = l & 15;

  const int fl = (int)blockIdx.x + 16 * (int)blockIdx.y;  // dispatch order
  const int bh = ((fl & 7) << 3) | ((fl >> 3) & 7);
  const int qpair = fl >> 6;  // 0..15
  const int b = bh >> 4, h = bh & 15;
  const size_t bT = (size_t)b * T_SEQ;
  const int M = NB * T_SEQ;

  const int srow = l >> 3;
  const int schunk = (l & 7) ^ srow;  // inverse-swizzled source chunk
  const __bf16* Kg = K + bT * DM + h * DK;
  const __bf16* Vg = VT + (size_t)(h * DK) * M + bT;
  const int rsw = lr & 7;
  // V b64 read offsets (within a Vs row): keys {c*16+4lg..+3} at chunk
  // (c*2+(lg>>1))^rsw, byte +8*(lg&1)
  const int vbq = (lg & 1) << 3;
  const int vc0 = lg >> 1;

  const int qbA = qpair, qbB = 31 - qpair;
  const int qrwA = qbA * 64 + w * 16, qrwB = qbB * 64 + w * 16;
  const int klastA = qbA * 64, klastB = qbB * 64;

  const __bf16* QpA = Q + (bT + qrwA + lr) * DM + h * DK;
  const __bf16* QpB = Q + (bT + qrwB + lr) * DM + h * DK;
  const bf16x8 qfA0 = *reinterpret_cast<const bf16x8*>(QpA + 8 * lg);
  const bf16x8 qfA1 = *reinterpret_cast<const bf16x8*>(QpA + 32 + 8 * lg);
  const bf16x8 qfB0 = *reinterpret_cast<const bf16x8*>(QpB + 8 * lg);
  const bf16x8 qfB1 = *reinterpret_cast<const bf16x8*>(QpB + 32 + 8 * lg);

  f32x4 o_accA[4] = {}, o_accB[4] = {};
  float lsumA = 0.f, lsumB = 0.f;

  auto STAGE = [&](int buf, int kbase) {
    #pragma unroll
    for (int i = 0; i < 2; ++i) {
      const int seg = w * 2 + i;
      gl_lds16(Kg + (size_t)(kbase + seg * 8 + srow) * DM + schunk * 8,
               &Ks[buf][seg * 8][0]);
      gl_lds16(Vg + (size_t)(seg * 8 + srow) * M + kbase + schunk * 8,
               &Vs[buf][seg * 8][0]);
    }
  };

  // one chunk's tile: swapped QK^T -> P in-register -> PV
  auto CHUNK = [&](const bf16x8& qf0, const bf16x8& qf1, f32x4* o_acc,
                   float& lsum, int qrw, bool masked, int k0, int buf,
                   const bf16x8* kf) {
    f32x4 s[4] = {};
    __builtin_amdgcn_s_setprio(1);
    #pragma unroll
    for (int ct = 0; ct < 4; ++ct) {
      s[ct] = __builtin_amdgcn_mfma_f32_16x16x32_bf16(kf[2 * ct], qf0, s[ct], 0, 0, 0);
      s[ct] = __builtin_amdgcn_mfma_f32_16x16x32_bf16(kf[2 * ct + 1], qf1, s[ct], 0, 0, 0);
    }
    __builtin_amdgcn_s_setprio(0);
    if (masked) {  // causal: lane holds q=lr, key=k0+16ct+4lg+r
      #pragma unroll
      for (int ct = 0; ct < 4; ++ct)
        #pragma unroll
        for (int r = 0; r < 4; ++r)
          if (k0 + 16 * ct + 4 * lg + r > qrw + lr) s[ct][r] = -1e30f;
    }
    // P = 2^S; pack straight into A-fragments (pi mapping, no LDS)
    unsigned pk[4][2];
    #pragma unroll
    for (int ct = 0; ct < 4; ++ct) {
      float p0 = exp2f(s[ct][0]), p1 = exp2f(s[ct][1]);
      float p2 = exp2f(s[ct][2]), p3 = exp2f(s[ct][3]);
      lsum += (p0 + p1) + (p2 + p3);
      pk[ct][0] = cvt_pk_bf16(p0, p1);
      pk[ct][1] = cvt_pk_bf16(p2, p3);
    }
    const bf16x8 pf0 = __builtin_bit_cast(bf16x8, i32x4{(int)pk[0][0], (int)pk[0][1],
                                                        (int)pk[1][0], (int)pk[1][1]});
    const bf16x8 pf1 = __builtin_bit_cast(bf16x8, i32x4{(int)pk[2][0], (int)pk[2][1],
                                                        (int)pk[3][0], (int)pk[3][1]});
    __builtin_amdgcn_s_setprio(1);
    #pragma unroll
    for (int dt = 0; dt < 4; ++dt) {
      const char* vb = (const char*)&Vs[buf][dt * 16 + lr][0];
      const i32x2 u00 = *reinterpret_cast<const i32x2*>(vb + (((vc0)     ^ rsw) << 4) + vbq);
      const i32x2 u01 = *reinterpret_cast<const i32x2*>(vb + (((vc0 + 2) ^ rsw) << 4) + vbq);
      const bf16x8 vf0 = __builtin_bit_cast(bf16x8, i32x4{u00[0], u00[1], u01[0], u01[1]});
      o_acc[dt] = __builtin_amdgcn_mfma_f32_16x16x32_bf16(pf0, vf0, o_acc[dt], 0, 0, 0);
      const i32x2 u10 = *reinterpret_cast<const i32x2*>(vb + (((vc0 + 4) ^ rsw) << 4) + vbq);
      const i32x2 u11 = *reinterpret_cast<const i32x2*>(vb + (((vc0 + 6) ^ rsw) << 4) + vbq);
      const bf16x8 vf1 = __builtin_bit_cast(bf16x8, i32x4{u10[0], u10[1], u11[0], u11[1]});
      o_acc[dt] = __builtin_amdgcn_mfma_f32_16x16x32_bf16(pf1, vf1, o_acc[dt], 0, 0, 0);
    }
    __builtin_amdgcn_s_setprio(0);
  };

  STAGE(0, 0);
  asm volatile("s_waitcnt vmcnt(0)" ::: "memory");
  __syncthreads();
  int buf = 0;

  for (int k0 = 0; k0 <= klastB; k0 += 64) {
    if (k0 + 64 <= klastB) STAGE(buf ^ 1, k0 + 64);

    // K fragments from LDS (swizzled b128 reads) -- shared by both chunks
    bf16x8 kf[8];
    #pragma unroll
    for (int ct = 0; ct < 4; ++ct) {
      const char* kb = (const char*)&Ks[buf][ct * 16 + lr][0];
      kf[2 * ct]     = *reinterpret_cast<const bf16x8*>(kb + ((lg ^ rsw) << 4));
      kf[2 * ct + 1] = *reinterpret_cast<const bf16x8*>(kb + (((lg + 4) ^ rsw) << 4));
    }

    CHUNK(qfB0, qfB1, o_accB, lsumB, qrwB, k0 == klastB, k0, buf, kf);
    if (k0 <= klastA)
      CHUNK(qfA0, qfA1, o_accA, lsumA, qrwA, k0 == klastA, k0, buf, kf);

    asm volatile("s_waitcnt vmcnt(0)" ::: "memory");
    __syncthreads();
    buf ^= 1;
  }

  // --- final l reduce + output, both chunks ---
  #pragma unroll
  for (int c = 0; c < 2; ++c) {
    const float lsum = c ? lsumA : lsumB;
    f32x4* oa = c ? o_accA : o_accB;
    const int qrw = c ? qrwA : qrwB;
    float v = lsum;             // per-lane sum for q = lr
    v += __shfl_xor(v, 16);
    v += __shfl_xor(v, 32);     // total over all keys, uniform in lg
    const float linv = 1.0f / v;
    float inv[4];
    #pragma unroll
    for (int r = 0; r < 4; ++r) inv[r] = __shfl(linv, 4 * lg + r);
    #pragma unroll
    for (int dt = 0; dt < 4; ++dt)
      #pragma unroll
      for (int r = 0; r < 4; ++r) {
        const int rg = qrw + 4 * lg + r;
        const int cg = h * DK + dt * 16 + lr;
        AO[(bT + rg) * DM + cg] = (__bf16)(oa[dt][r] * inv[r]);
      }
  }
}

extern "C" void kernel_launch(void* const* d_in, const int* in_sizes, int n_in,
                              void* d_out, int out_size, void* d_ws, size_t ws_size,
                              hipStream_t stream) {
  (void)in_sizes; (void)n_in; (void)out_size; (void)ws_size;
  const float* X  = (const float*)d_in[0];
  const float* Wq = (const float*)d_in[1];
  const float* Wk = (const float*)d_in[2];
  const float* Wv = (const float*)d_in[3];
  const float* Wo = (const float*)d_in[4];
  float* OUT = (float*)d_out;

  char* ws = (char*)d_ws;
  const size_t SZ_X = (size_t)NB * T_SEQ * DM * 2;  // 16.78 MB
  const size_t SZ_W = (size_t)DM * DM * 2;          // 2.10 MB
  __bf16* Xb  = (__bf16*)ws; ws += SZ_X;
  __bf16* Wqb = (__bf16*)ws; ws += SZ_W;
  __bf16* Wkb = (__bf16*)ws; ws += SZ_W;
  __bf16* Wvb = (__bf16*)ws; ws += SZ_W;
  __bf16* Wob = (__bf16*)ws; ws += SZ_W;
  __bf16* Qb  = (__bf16*)ws; ws += SZ_X;
  __bf16* Kb  = (__bf16*)ws; ws += SZ_X;
  __bf16* VTb = (__bf16*)ws; ws += SZ_X;
  __bf16* AOb = (__bf16*)ws; ws += SZ_X;

  const int M = NB * T_SEQ;  // 8192

  cast_f32_to_bf16<<<(M * DM / 4) / 256, 256, 0, stream>>>(X, Xb, M * DM / 4);
  cast_weights<<<dim3(DM * DM / 4 / 256, 4), 256, 0, stream>>>(Wq, Wk, Wv, Wo,
                                                               Wqb, Wkb, Wvb, Wob);

  // Q = (X @ Wq^T) * 0.125*log2e  (scale folded into epilogue)
  gemm_nt<__bf16, true ><<<dim3(DM / 128, M / 128), 256, 0, stream>>>(Xb, Wqb, Qb, M, DM, DM);
  gemm_nt<__bf16, false><<<dim3(DM / 128, M / 128), 256, 0, stream>>>(Xb, Wkb, Kb, M, DM, DM);
  // VT[n][m] = sum_k Wv[n][k] X[m][k]  -> V transposed, [DM, M]
  gemm_nt<__bf16, false><<<dim3(M / 128, DM / 128), 256, 0, stream>>>(Wvb, Xb, VTb, DM, M, DM);
  // attention
  attn_fwd<<<dim3(T_SEQ / 128, NB * NH), 256, 0, stream>>>(Qb, Kb, VTb, AOb);
  // OUT = AO @ Wo^T (fp32 out)
  gemm_nt<float, false><<<dim3(DM / 128, M / 128), 256, 0, stream>>>(AOb, Wob, OUT, M, DM, DM);
}

// Round 9
// 172.230 us; speedup vs baseline: 1.1012x; 1.1012x over previous
//
#include <hip/hip_runtime.h>
#include <hip/hip_bf16.h>

#define T_SEQ 2048
#define NB 4
#define NH 16
#define DK 64
#define DM 1024
#define QKS 2048  // row stride of fused [Q|K] buffer

typedef __attribute__((ext_vector_type(8))) __bf16 bf16x8;
typedef __attribute__((ext_vector_type(4))) __bf16 bf16x4;
typedef __attribute__((ext_vector_type(4))) float f32x4;
typedef __attribute__((ext_vector_type(2))) int i32x2;
typedef __attribute__((ext_vector_type(4))) int i32x4;

// async global->LDS, 16B per lane, wave-uniform LDS base + lane*16
__device__ __forceinline__ void gl_lds16(const __bf16* g, __bf16* l) {
  __builtin_amdgcn_global_load_lds(
      (const __attribute__((address_space(1))) void*)g,
      (__attribute__((address_space(3))) void*)l,
      16, 0, 0);
}

__device__ __forceinline__ unsigned cvt_pk_bf16(float lo, float hi) {
  unsigned r;
  asm("v_cvt_pk_bf16_f32 %0, %1, %2" : "=v"(r) : "v"(lo), "v"(hi));
  return r;
}

// ---------------- cast fp32 -> bf16, vectorized ----------------
__global__ __launch_bounds__(256) void cast_f32_to_bf16(const float* __restrict__ in,
                                                        __bf16* __restrict__ out, int n4) {
  int i = blockIdx.x * 256 + threadIdx.x;
  if (i >= n4) return;
  float4 v = reinterpret_cast<const float4*>(in)[i];
  bf16x4 o;
  o[0] = (__bf16)v.x; o[1] = (__bf16)v.y; o[2] = (__bf16)v.z; o[3] = (__bf16)v.w;
  reinterpret_cast<bf16x4*>(out)[i] = o;
}

// fused cast of the four weight matrices (each DM*DM fp32)
__global__ __launch_bounds__(256) void cast_weights(const float* __restrict__ a,
                                                    const float* __restrict__ b,
                                                    const float* __restrict__ c,
                                                    const float* __restrict__ d,
                                                    __bf16* __restrict__ oa,
                                                    __bf16* __restrict__ ob,
                                                    __bf16* __restrict__ oc,
                                                    __bf16* __restrict__ od) {
  const int which = blockIdx.y;
  const float* in = (which == 0) ? a : (which == 1) ? b : (which == 2) ? c : d;
  __bf16* out = (which == 0) ? oa : (which == 1) ? ob : (which == 2) ? oc : od;
  int i = blockIdx.x * 256 + threadIdx.x;
  float4 v = reinterpret_cast<const float4*>(in)[i];
  bf16x4 o;
  o[0] = (__bf16)v.x; o[1] = (__bf16)v.y; o[2] = (__bf16)v.z; o[3] = (__bf16)v.w;
  reinterpret_cast<bf16x4*>(out)[i] = o;
}

// ---------------- NT GEMM (m97-style): C[M,N] = A[M,K] * B[N,K]^T ---------
// MODE 0: plain.  MODE 1: scale cols <1024 by 0.125*log2e (fused QK).
// MODE 2: sigma-permute N within 32-groups (VT for attn PV fragments).
template<typename CT, int MODE>
__global__ __launch_bounds__(256, 2) void gemm_nt(const __bf16* __restrict__ A,
                                                  const __bf16* __restrict__ B,
                                                  CT* __restrict__ C,
                                                  int M, int N, int K) {
  __shared__ alignas(16) __bf16 As[128][64];
  __shared__ alignas(16) __bf16 Bs[128][64];
  const int tid = threadIdx.x;
  const int m0 = blockIdx.y * 128, n0 = blockIdx.x * 128;
  const int w = tid >> 6, l = tid & 63, lg = l >> 4, lr = l & 15;
  const int wr = (w >> 1) * 64, wc = (w & 1) * 64;
  const int srow = l >> 3;              // 0..7 within 8-row segment
  const int schunk = (l & 7) ^ srow;    // inverse-swizzled source 16B chunk

  f32x4 acc[4][4] = {};
  const int rsw = lr & 7;

  for (int k0 = 0; k0 < K; k0 += 64) {
    __syncthreads();
    #pragma unroll
    for (int j = 0; j < 4; ++j) {
      const int rbase = (w * 4 + j) * 8;
      gl_lds16(A + (size_t)(m0 + rbase + srow) * K + k0 + schunk * 8, &As[rbase][0]);
      gl_lds16(B + (size_t)(n0 + rbase + srow) * K + k0 + schunk * 8, &Bs[rbase][0]);
    }
    asm volatile("s_waitcnt vmcnt(0)" ::: "memory");
    __syncthreads();
    #pragma unroll
    for (int kk = 0; kk < 2; ++kk) {
      bf16x8 af[4], bfr[4];
      #pragma unroll
      for (int mt = 0; mt < 4; ++mt) {
        const char* p = (const char*)&As[wr + mt * 16 + lr][0];
        af[mt] = *reinterpret_cast<const bf16x8*>(p + (((kk * 4 + lg) ^ rsw) << 4));
      }
      #pragma unroll
      for (int nt = 0; nt < 4; ++nt) {
        const char* p = (const char*)&Bs[wc + nt * 16 + lr][0];
        bfr[nt] = *reinterpret_cast<const bf16x8*>(p + (((kk * 4 + lg) ^ rsw) << 4));
      }
      __builtin_amdgcn_s_setprio(1);
      #pragma unroll
      for (int mt = 0; mt < 4; ++mt)
        #pragma unroll
        for (int nt = 0; nt < 4; ++nt)
          acc[mt][nt] = __builtin_amdgcn_mfma_f32_16x16x32_bf16(af[mt], bfr[nt], acc[mt][nt], 0, 0, 0);
      __builtin_amdgcn_s_setprio(0);
    }
  }
  const float qsc = (MODE == 1 && n0 < 1024) ? 0.18033688f : 1.0f;
  #pragma unroll
  for (int mt = 0; mt < 4; ++mt)
    #pragma unroll
    for (int nt = 0; nt < 4; ++nt)
      #pragma unroll
      for (int r = 0; r < 4; ++r) {
        const int mg = m0 + wr + mt * 16 + 4 * lg + r;
        int ng = n0 + wc + nt * 16 + lr;
        if (MODE == 2)  // sigma^-1 within 32-key group: key kappa -> slot
          ng = (ng & ~31) | (8 * (lr >> 2) + (lr & 3) + ((nt & 1) << 2));
        float v = acc[mt][nt][r];
        if (MODE == 1) v *= qsc;
        C[(size_t)mg * N + ng] = (CT)v;
      }
}

// ---------------- causal flash attention ----------------------------------
// grid: 1024 blocks; XCD remap: bh = (f&7)*8|(f>>3)&7, qpair = f>>6.
// Merged dual-chunk; no-max softmax (P = 2^S); swapped QK^T (lane q=lr).
// VT is sigma-permuted in memory -> V B-fragments are plain b128 reads
// (identical form to kf; conflict-free), shared across both chunks.
__global__ __launch_bounds__(256, 3) void attn_fwd(const __bf16* __restrict__ QK,
                                                   const __bf16* __restrict__ VT,
                                                   __bf16* __restrict__ AO) {
  __shared__ alignas(16) __bf16 Ks[2][64][64];
  __shared__ alignas(16) __bf16 Vs[2][64][64];  // sigma-permuted V^T tile
  const int tid = threadIdx.x;
  const int w = tid >> 6, l = tid & 63, lg = l >> 4, lr = l & 15;

  const int fl = (int)blockIdx.x + 16 * (int)blockIdx.y;  // dispatch order
  const int bh = ((fl & 7) << 3) | ((fl >> 3) & 7);
  const int qpair = fl >> 6;  // 0..15
  const int b = bh >> 4, h = bh & 15;
  const size_t bT = (size_t)b * T_SEQ;
  const int M = NB * T_SEQ;

  const int srow = l >> 3;
  const int schunk = (l & 7) ^ srow;  // inverse-swizzled source chunk
  const __bf16* Kg = QK + bT * QKS + 1024 + h * DK;   // K half of fused buffer
  const __bf16* Vg = VT + (size_t)(h * DK) * M + bT;
  const int rsw = lr & 7;

  const int qbA = qpair, qbB = 31 - qpair;
  const int qrwA = qbA * 64 + w * 16, qrwB = qbB * 64 + w * 16;
  const int klastA = qbA * 64, klastB = qbB * 64;

  const __bf16* QpA = QK + (bT + qrwA + lr) * QKS + h * DK;
  const __bf16* QpB = QK + (bT + qrwB + lr) * QKS + h * DK;
  const bf16x8 qfA0 = *reinterpret_cast<const bf16x8*>(QpA + 8 * lg);
  const bf16x8 qfA1 = *reinterpret_cast<const bf16x8*>(QpA + 32 + 8 * lg);
  const bf16x8 qfB0 = *reinterpret_cast<const bf16x8*>(QpB + 8 * lg);
  const bf16x8 qfB1 = *reinterpret_cast<const bf16x8*>(QpB + 32 + 8 * lg);

  f32x4 o_accA[4] = {}, o_accB[4] = {};
  float lsumA = 0.f, lsumB = 0.f;

  auto STAGE = [&](int buf, int kbase) {
    #pragma unroll
    for (int i = 0; i < 2; ++i) {
      const int seg = w * 2 + i;
      gl_lds16(Kg + (size_t)(kbase + seg * 8 + srow) * QKS + schunk * 8,
               &Ks[buf][seg * 8][0]);
      gl_lds16(Vg + (size_t)(seg * 8 + srow) * M + kbase + schunk * 8,
               &Vs[buf][seg * 8][0]);
    }
  };

  // one chunk's tile: swapped QK^T -> P in-register -> PV (vf shared)
  auto CHUNK = [&](const bf16x8& qf0, const bf16x8& qf1, f32x4* o_acc,
                   float& lsum, int qrw, bool masked, int k0,
                   const bf16x8* kf, const bf16x8* vf) {
    f32x4 s[4] = {};
    __builtin_amdgcn_s_setprio(1);
    #pragma unroll
    for (int ct = 0; ct < 4; ++ct) {
      s[ct] = __builtin_amdgcn_mfma_f32_16x16x32_bf16(kf[2 * ct], qf0, s[ct], 0, 0, 0);
      s[ct] = __builtin_amdgcn_mfma_f32_16x16x32_bf16(kf[2 * ct + 1], qf1, s[ct], 0, 0, 0);
    }
    __builtin_amdgcn_s_setprio(0);
    if (masked) {  // causal: lane holds q=lr, key=k0+16ct+4lg+r
      #pragma unroll
      for (int ct = 0; ct < 4; ++ct)
        #pragma unroll
        for (int r = 0; r < 4; ++r)
          if (k0 + 16 * ct + 4 * lg + r > qrw + lr) s[ct][r] = -1e30f;
    }
    // P = 2^S; pack straight into A-fragments (sigma mapping, no LDS)
    unsigned pk[4][2];
    #pragma unroll
    for (int ct = 0; ct < 4; ++ct) {
      float p0 = exp2f(s[ct][0]), p1 = exp2f(s[ct][1]);
      float p2 = exp2f(s[ct][2]), p3 = exp2f(s[ct][3]);
      lsum += (p0 + p1) + (p2 + p3);
      pk[ct][0] = cvt_pk_bf16(p0, p1);
      pk[ct][1] = cvt_pk_bf16(p2, p3);
    }
    const bf16x8 pf0 = __builtin_bit_cast(bf16x8, i32x4{(int)pk[0][0], (int)pk[0][1],
                                                        (int)pk[1][0], (int)pk[1][1]});
    const bf16x8 pf1 = __builtin_bit_cast(bf16x8, i32x4{(int)pk[2][0], (int)pk[2][1],
                                                        (int)pk[3][0], (int)pk[3][1]});
    __builtin_amdgcn_s_setprio(1);
    #pragma unroll
    for (int dt = 0; dt < 4; ++dt) {
      o_acc[dt] = __builtin_amdgcn_mfma_f32_16x16x32_bf16(pf0, vf[2 * dt],     o_acc[dt], 0, 0, 0);
      o_acc[dt] = __builtin_amdgcn_mfma_f32_16x16x32_bf16(pf1, vf[2 * dt + 1], o_acc[dt], 0, 0, 0);
    }
    __builtin_amdgcn_s_setprio(0);
  };

  STAGE(0, 0);
  asm volatile("s_waitcnt vmcnt(0)" ::: "memory");
  __syncthreads();
  int buf = 0;

  for (int k0 = 0; k0 <= klastB; k0 += 64) {
    if (k0 + 64 <= klastB) STAGE(buf ^ 1, k0 + 64);

    // K and V fragments from LDS (swizzled b128) -- shared by both chunks
    bf16x8 kf[8], vf[8];
    #pragma unroll
    for (int ct = 0; ct < 4; ++ct) {
      const char* kb = (const char*)&Ks[buf][ct * 16 + lr][0];
      kf[2 * ct]     = *reinterpret_cast<const bf16x8*>(kb + ((lg ^ rsw) << 4));
      kf[2 * ct + 1] = *reinterpret_cast<const bf16x8*>(kb + (((lg + 4) ^ rsw) << 4));
      const char* vb = (const char*)&Vs[buf][ct * 16 + lr][0];
      vf[2 * ct]     = *reinterpret_cast<const bf16x8*>(vb + ((lg ^ rsw) << 4));
      vf[2 * ct + 1] = *reinterpret_cast<const bf16x8*>(vb + (((lg + 4) ^ rsw) << 4));
    }

    CHUNK(qfB0, qfB1, o_accB, lsumB, qrwB, k0 == klastB, k0, kf, vf);
    if (k0 <= klastA)
      CHUNK(qfA0, qfA1, o_accA, lsumA, qrwA, k0 == klastA, k0, kf, vf);

    asm volatile("s_waitcnt vmcnt(0)" ::: "memory");
    __syncthreads();
    buf ^= 1;
  }

  // --- final l reduce + output, both chunks ---
  #pragma unroll
  for (int c = 0; c < 2; ++c) {
    const float lsum = c ? lsumA : lsumB;
    f32x4* oa = c ? o_accA : o_accB;
    const int qrw = c ? qrwA : qrwB;
    float v = lsum;             // per-lane sum for q = lr
    v += __shfl_xor(v, 16);
    v += __shfl_xor(v, 32);     // total over all keys, uniform in lg
    const float linv = 1.0f / v;
    float inv[4];
    #pragma unroll
    for (int r = 0; r < 4; ++r) inv[r] = __shfl(linv, 4 * lg + r);
    #pragma unroll
    for (int dt = 0; dt < 4; ++dt)
      #pragma unroll
      for (int r = 0; r < 4; ++r) {
        const int rg = qrw + 4 * lg + r;
        const int cg = h * DK + dt * 16 + lr;
        AO[(bT + rg) * DM + cg] = (__bf16)(oa[dt][r] * inv[r]);
      }
  }
}

extern "C" void kernel_launch(void* const* d_in, const int* in_sizes, int n_in,
                              void* d_out, int out_size, void* d_ws, size_t ws_size,
                              hipStream_t stream) {
  (void)in_sizes; (void)n_in; (void)out_size; (void)ws_size;
  const float* X  = (const float*)d_in[0];
  const float* Wq = (const float*)d_in[1];
  const float* Wk = (const float*)d_in[2];
  const float* Wv = (const float*)d_in[3];
  const float* Wo = (const float*)d_in[4];
  float* OUT = (float*)d_out;

  char* ws = (char*)d_ws;
  const size_t SZ_X  = (size_t)NB * T_SEQ * DM * 2;   // 16.78 MB
  const size_t SZ_W  = (size_t)DM * DM * 2;           // 2.10 MB
  const size_t SZ_QK = (size_t)NB * T_SEQ * QKS * 2;  // 33.55 MB
  __bf16* Xb  = (__bf16*)ws; ws += SZ_X;
  __bf16* Wqb = (__bf16*)ws; ws += SZ_W;   // Wqb and Wkb contiguous ->
  __bf16* Wkb = (__bf16*)ws; ws += SZ_W;   // fused [Wq;Wk] of 2048x1024
  __bf16* Wvb = (__bf16*)ws; ws += SZ_W;
  __bf16* Wob = (__bf16*)ws; ws += SZ_W;
  __bf16* QKb = (__bf16*)ws; ws += SZ_QK;
  __bf16* VTb = (__bf16*)ws; ws += SZ_X;
  __bf16* AOb = (__bf16*)ws; ws += SZ_X;

  const int M = NB * T_SEQ;  // 8192

  cast_f32_to_bf16<<<(M * DM / 4) / 256, 256, 0, stream>>>(X, Xb, M * DM / 4);
  cast_weights<<<dim3(DM * DM / 4 / 256, 4), 256, 0, stream>>>(Wq, Wk, Wv, Wo,
                                                               Wqb, Wkb, Wvb, Wob);

  // [Q|K] = X @ [Wq;Wk]^T, Q cols pre-scaled by 0.125*log2e
  gemm_nt<__bf16, 1><<<dim3(QKS / 128, M / 128), 256, 0, stream>>>(Xb, Wqb, QKb, M, QKS, DM);
  // VT[d][key'] = sigma-permuted V^T  (V = X @ Wv^T)
  gemm_nt<__bf16, 2><<<dim3(M / 128, DM / 128), 256, 0, stream>>>(Wvb, Xb, VTb, DM, M, DM);
  // attention
  attn_fwd<<<dim3(T_SEQ / 128, NB * NH), 256, 0, stream>>>(QKb, VTb, AOb);
  // OUT = AO @ Wo^T (fp32 out)
  gemm_nt<float, 0><<<dim3(DM / 128, M / 128), 256, 0, stream>>>(AOb, Wob, OUT, M, DM, DM);
}

// Round 10
// 162.532 us; speedup vs baseline: 1.1670x; 1.0597x over previous
//
#include <hip/hip_runtime.h>
#include <hip/hip_bf16.h>

#define T_SEQ 2048
#define NB 4
#define NH 16
#define DK 64
#define DM 1024
#define QKS 2048  // row stride of fused [Q|K] buffer

typedef __attribute__((ext_vector_type(8))) __bf16 bf16x8;
typedef __attribute__((ext_vector_type(4))) __bf16 bf16x4;
typedef __attribute__((ext_vector_type(4))) float f32x4;
typedef __attribute__((ext_vector_type(2))) int i32x2;
typedef __attribute__((ext_vector_type(4))) int i32x4;

// async global->LDS, 16B per lane, wave-uniform LDS base + lane*16
__device__ __forceinline__ void gl_lds16(const __bf16* g, __bf16* l) {
  __builtin_amdgcn_global_load_lds(
      (const __attribute__((address_space(1))) void*)g,
      (__attribute__((address_space(3))) void*)l,
      16, 0, 0);
}

__device__ __forceinline__ unsigned cvt_pk_bf16(float lo, float hi) {
  unsigned r;
  asm("v_cvt_pk_bf16_f32 %0, %1, %2" : "=v"(r) : "v"(lo), "v"(hi));
  return r;
}

// ---------------- cast fp32 -> bf16, vectorized ----------------
__global__ __launch_bounds__(256) void cast_f32_to_bf16(const float* __restrict__ in,
                                                        __bf16* __restrict__ out, int n4) {
  int i = blockIdx.x * 256 + threadIdx.x;
  if (i >= n4) return;
  float4 v = reinterpret_cast<const float4*>(in)[i];
  bf16x4 o;
  o[0] = (__bf16)v.x; o[1] = (__bf16)v.y; o[2] = (__bf16)v.z; o[3] = (__bf16)v.w;
  reinterpret_cast<bf16x4*>(out)[i] = o;
}

// fused cast of the four weight matrices (each DM*DM fp32)
__global__ __launch_bounds__(256) void cast_weights(const float* __restrict__ a,
                                                    const float* __restrict__ b,
                                                    const float* __restrict__ c,
                                                    const float* __restrict__ d,
                                                    __bf16* __restrict__ oa,
                                                    __bf16* __restrict__ ob,
                                                    __bf16* __restrict__ oc,
                                                    __bf16* __restrict__ od) {
  const int which = blockIdx.y;
  const float* in = (which == 0) ? a : (which == 1) ? b : (which == 2) ? c : d;
  __bf16* out = (which == 0) ? oa : (which == 1) ? ob : (which == 2) ? oc : od;
  int i = blockIdx.x * 256 + threadIdx.x;
  float4 v = reinterpret_cast<const float4*>(in)[i];
  bf16x4 o;
  o[0] = (__bf16)v.x; o[1] = (__bf16)v.y; o[2] = (__bf16)v.z; o[3] = (__bf16)v.w;
  reinterpret_cast<bf16x4*>(out)[i] = o;
}

// ---------------- NT GEMM (m97-style): C[M,N] = A[M,K] * B[N,K]^T ---------
// MODE 0: plain.  MODE 1: scale cols <1024 by 0.125*log2e (fused QK).
// MODE 2: sigma-permute N within 32-groups (VT for attn PV fragments).
template<typename CT, int MODE>
__global__ __launch_bounds__(256, 2) void gemm_nt(const __bf16* __restrict__ A,
                                                  const __bf16* __restrict__ B,
                                                  CT* __restrict__ C,
                                                  int M, int N, int K) {
  __shared__ alignas(16) __bf16 As[128][64];
  __shared__ alignas(16) __bf16 Bs[128][64];
  const int tid = threadIdx.x;
  const int m0 = blockIdx.y * 128, n0 = blockIdx.x * 128;
  const int w = tid >> 6, l = tid & 63, lg = l >> 4, lr = l & 15;
  const int wr = (w >> 1) * 64, wc = (w & 1) * 64;
  const int srow = l >> 3;              // 0..7 within 8-row segment
  const int schunk = (l & 7) ^ srow;    // inverse-swizzled source 16B chunk

  f32x4 acc[4][4] = {};
  const int rsw = lr & 7;

  for (int k0 = 0; k0 < K; k0 += 64) {
    __syncthreads();
    #pragma unroll
    for (int j = 0; j < 4; ++j) {
      const int rbase = (w * 4 + j) * 8;
      gl_lds16(A + (size_t)(m0 + rbase + srow) * K + k0 + schunk * 8, &As[rbase][0]);
      gl_lds16(B + (size_t)(n0 + rbase + srow) * K + k0 + schunk * 8, &Bs[rbase][0]);
    }
    asm volatile("s_waitcnt vmcnt(0)" ::: "memory");
    __syncthreads();
    #pragma unroll
    for (int kk = 0; kk < 2; ++kk) {
      bf16x8 af[4], bfr[4];
      #pragma unroll
      for (int mt = 0; mt < 4; ++mt) {
        const char* p = (const char*)&As[wr + mt * 16 + lr][0];
        af[mt] = *reinterpret_cast<const bf16x8*>(p + (((kk * 4 + lg) ^ rsw) << 4));
      }
      #pragma unroll
      for (int nt = 0; nt < 4; ++nt) {
        const char* p = (const char*)&Bs[wc + nt * 16 + lr][0];
        bfr[nt] = *reinterpret_cast<const bf16x8*>(p + (((kk * 4 + lg) ^ rsw) << 4));
      }
      __builtin_amdgcn_s_setprio(1);
      #pragma unroll
      for (int mt = 0; mt < 4; ++mt)
        #pragma unroll
        for (int nt = 0; nt < 4; ++nt)
          acc[mt][nt] = __builtin_amdgcn_mfma_f32_16x16x32_bf16(af[mt], bfr[nt], acc[mt][nt], 0, 0, 0);
      __builtin_amdgcn_s_setprio(0);
    }
  }
  const float qsc = (MODE == 1 && n0 < 1024) ? 0.18033688f : 1.0f;
  #pragma unroll
  for (int mt = 0; mt < 4; ++mt)
    #pragma unroll
    for (int nt = 0; nt < 4; ++nt)
      #pragma unroll
      for (int r = 0; r < 4; ++r) {
        const int mg = m0 + wr + mt * 16 + 4 * lg + r;
        int ng = n0 + wc + nt * 16 + lr;
        if (MODE == 2)  // sigma^-1 within 32-key group: key kappa -> slot
          ng = (ng & ~31) | (8 * (lr >> 2) + (lr & 3) + ((nt & 1) << 2));
        float v = acc[mt][nt][r];
        if (MODE == 1) v *= qsc;
        C[(size_t)mg * N + ng] = (CT)v;
      }
}

// ---------------- causal flash attention ----------------------------------
// grid: 512 blocks (8 per bh); XCD remap: bh = (f&7)*8|(f>>3)&7, c = f>>6.
// QUAD-chunk merge: block processes chunks {c, 15-c, 16+c, 31-c} (activity
// nests A<=B<=C<=D) in ONE K-loop; kf/vf LDS reads per tile are shared by
// all four chunks (64 q-rows per wave per read set -> LDS pipe halved).
// No-max softmax (P = 2^S); swapped QK^T; sigma-permuted VT; no LDS P.
__global__ __launch_bounds__(256, 2) void attn_fwd(const __bf16* __restrict__ QK,
                                                   const __bf16* __restrict__ VT,
                                                   __bf16* __restrict__ AO) {
  __shared__ alignas(16) __bf16 Ks[2][64][64];
  __shared__ alignas(16) __bf16 Vs[2][64][64];  // sigma-permuted V^T tile
  const int tid = threadIdx.x;
  const int w = tid >> 6, l = tid & 63, lg = l >> 4, lr = l & 15;

  const int fl = (int)blockIdx.x + 8 * (int)blockIdx.y;  // dispatch order
  const int bh = ((fl & 7) << 3) | ((fl >> 3) & 7);
  const int c = fl >> 6;  // 0..7
  const int b = bh >> 4, h = bh & 15;
  const size_t bT = (size_t)b * T_SEQ;
  const int M = NB * T_SEQ;

  const int srow = l >> 3;
  const int schunk = (l & 7) ^ srow;  // inverse-swizzled source chunk
  const __bf16* Kg = QK + bT * QKS + 1024 + h * DK;   // K half of fused buffer
  const __bf16* Vg = VT + (size_t)(h * DK) * M + bT;
  const int rsw = lr & 7;

  // chunk q-block indices (64-row chunks), nested activity A<=B<=C<=D
  const int qbA = c, qbB = 15 - c, qbC = 16 + c, qbD = 31 - c;
  const int qrwA = qbA * 64 + w * 16, qrwB = qbB * 64 + w * 16;
  const int qrwC = qbC * 64 + w * 16, qrwD = qbD * 64 + w * 16;
  const int klA = qbA * 64, klB = qbB * 64, klC = qbC * 64, klD = qbD * 64;

  const __bf16* QpA = QK + (bT + qrwA + lr) * QKS + h * DK;
  const __bf16* QpB = QK + (bT + qrwB + lr) * QKS + h * DK;
  const __bf16* QpC = QK + (bT + qrwC + lr) * QKS + h * DK;
  const __bf16* QpD = QK + (bT + qrwD + lr) * QKS + h * DK;
  const bf16x8 qfA0 = *reinterpret_cast<const bf16x8*>(QpA + 8 * lg);
  const bf16x8 qfA1 = *reinterpret_cast<const bf16x8*>(QpA + 32 + 8 * lg);
  const bf16x8 qfB0 = *reinterpret_cast<const bf16x8*>(QpB + 8 * lg);
  const bf16x8 qfB1 = *reinterpret_cast<const bf16x8*>(QpB + 32 + 8 * lg);
  const bf16x8 qfC0 = *reinterpret_cast<const bf16x8*>(QpC + 8 * lg);
  const bf16x8 qfC1 = *reinterpret_cast<const bf16x8*>(QpC + 32 + 8 * lg);
  const bf16x8 qfD0 = *reinterpret_cast<const bf16x8*>(QpD + 8 * lg);
  const bf16x8 qfD1 = *reinterpret_cast<const bf16x8*>(QpD + 32 + 8 * lg);

  f32x4 o_accA[4] = {}, o_accB[4] = {}, o_accC[4] = {}, o_accD[4] = {};
  float lsumA = 0.f, lsumB = 0.f, lsumC = 0.f, lsumD = 0.f;

  auto STAGE = [&](int buf, int kbase) {
    #pragma unroll
    for (int i = 0; i < 2; ++i) {
      const int seg = w * 2 + i;
      gl_lds16(Kg + (size_t)(kbase + seg * 8 + srow) * QKS + schunk * 8,
               &Ks[buf][seg * 8][0]);
      gl_lds16(Vg + (size_t)(seg * 8 + srow) * M + kbase + schunk * 8,
               &Vs[buf][seg * 8][0]);
    }
  };

  // one chunk's tile: swapped QK^T -> P in-register -> PV (kf/vf shared)
  auto CHUNK = [&](const bf16x8& qf0, const bf16x8& qf1, f32x4* o_acc,
                   float& lsum, int qrw, bool masked, int k0,
                   const bf16x8* kf, const bf16x8* vf) {
    f32x4 s[4] = {};
    __builtin_amdgcn_s_setprio(1);
    #pragma unroll
    for (int ct = 0; ct < 4; ++ct) {
      s[ct] = __builtin_amdgcn_mfma_f32_16x16x32_bf16(kf[2 * ct], qf0, s[ct], 0, 0, 0);
      s[ct] = __builtin_amdgcn_mfma_f32_16x16x32_bf16(kf[2 * ct + 1], qf1, s[ct], 0, 0, 0);
    }
    __builtin_amdgcn_s_setprio(0);
    if (masked) {  // causal: lane holds q=lr, key=k0+16ct+4lg+r
      #pragma unroll
      for (int ct = 0; ct < 4; ++ct)
        #pragma unroll
        for (int r = 0; r < 4; ++r)
          if (k0 + 16 * ct + 4 * lg + r > qrw + lr) s[ct][r] = -1e30f;
    }
    // P = 2^S; pack straight into A-fragments (sigma mapping, no LDS)
    unsigned pk[4][2];
    #pragma unroll
    for (int ct = 0; ct < 4; ++ct) {
      float p0 = exp2f(s[ct][0]), p1 = exp2f(s[ct][1]);
      float p2 = exp2f(s[ct][2]), p3 = exp2f(s[ct][3]);
      lsum += (p0 + p1) + (p2 + p3);
      pk[ct][0] = cvt_pk_bf16(p0, p1);
      pk[ct][1] = cvt_pk_bf16(p2, p3);
    }
    const bf16x8 pf0 = __builtin_bit_cast(bf16x8, i32x4{(int)pk[0][0], (int)pk[0][1],
                                                        (int)pk[1][0], (int)pk[1][1]});
    const bf16x8 pf1 = __builtin_bit_cast(bf16x8, i32x4{(int)pk[2][0], (int)pk[2][1],
                                                        (int)pk[3][0], (int)pk[3][1]});
    __builtin_amdgcn_s_setprio(1);
    #pragma unroll
    for (int dt = 0; dt < 4; ++dt) {
      o_acc[dt] = __builtin_amdgcn_mfma_f32_16x16x32_bf16(pf0, vf[2 * dt],     o_acc[dt], 0, 0, 0);
      o_acc[dt] = __builtin_amdgcn_mfma_f32_16x16x32_bf16(pf1, vf[2 * dt + 1], o_acc[dt], 0, 0, 0);
    }
    __builtin_amdgcn_s_setprio(0);
  };

  STAGE(0, 0);
  asm volatile("s_waitcnt vmcnt(0)" ::: "memory");
  __syncthreads();
  int buf = 0;

  for (int k0 = 0; k0 <= klD; k0 += 64) {
    if (k0 + 64 <= klD) STAGE(buf ^ 1, k0 + 64);

    // K and V fragments from LDS (swizzled b128) -- shared by all 4 chunks
    bf16x8 kf[8], vf[8];
    #pragma unroll
    for (int ct = 0; ct < 4; ++ct) {
      const char* kb = (const char*)&Ks[buf][ct * 16 + lr][0];
      kf[2 * ct]     = *reinterpret_cast<const bf16x8*>(kb + ((lg ^ rsw) << 4));
      kf[2 * ct + 1] = *reinterpret_cast<const bf16x8*>(kb + (((lg + 4) ^ rsw) << 4));
      const char* vb = (const char*)&Vs[buf][ct * 16 + lr][0];
      vf[2 * ct]     = *reinterpret_cast<const bf16x8*>(vb + ((lg ^ rsw) << 4));
      vf[2 * ct + 1] = *reinterpret_cast<const bf16x8*>(vb + (((lg + 4) ^ rsw) << 4));
    }

    CHUNK(qfD0, qfD1, o_accD, lsumD, qrwD, k0 == klD, k0, kf, vf);
    if (k0 <= klC) CHUNK(qfC0, qfC1, o_accC, lsumC, qrwC, k0 == klC, k0, kf, vf);
    if (k0 <= klB) CHUNK(qfB0, qfB1, o_accB, lsumB, qrwB, k0 == klB, k0, kf, vf);
    if (k0 <= klA) CHUNK(qfA0, qfA1, o_accA, lsumA, qrwA, k0 == klA, k0, kf, vf);

    asm volatile("s_waitcnt vmcnt(0)" ::: "memory");
    __syncthreads();
    buf ^= 1;
  }

  // --- final l reduce + output, all 4 chunks ---
  #pragma unroll
  for (int cc = 0; cc < 4; ++cc) {
    const float lsum = (cc == 0) ? lsumA : (cc == 1) ? lsumB : (cc == 2) ? lsumC : lsumD;
    f32x4* oa = (cc == 0) ? o_accA : (cc == 1) ? o_accB : (cc == 2) ? o_accC : o_accD;
    const int qrw = (cc == 0) ? qrwA : (cc == 1) ? qrwB : (cc == 2) ? qrwC : qrwD;
    float v = lsum;             // per-lane sum for q = lr
    v += __shfl_xor(v, 16);
    v += __shfl_xor(v, 32);     // total over all keys, uniform in lg
    const float linv = 1.0f / v;
    float inv[4];
    #pragma unroll
    for (int r = 0; r < 4; ++r) inv[r] = __shfl(linv, 4 * lg + r);
    #pragma unroll
    for (int dt = 0; dt < 4; ++dt)
      #pragma unroll
      for (int r = 0; r < 4; ++r) {
        const int rg = qrw + 4 * lg + r;
        const int cg = h * DK + dt * 16 + lr;
        AO[(bT + rg) * DM + cg] = (__bf16)(oa[dt][r] * inv[r]);
      }
  }
}

extern "C" void kernel_launch(void* const* d_in, const int* in_sizes, int n_in,
                              void* d_out, int out_size, void* d_ws, size_t ws_size,
                              hipStream_t stream) {
  (void)in_sizes; (void)n_in; (void)out_size; (void)ws_size;
  const float* X  = (const float*)d_in[0];
  const float* Wq = (const float*)d_in[1];
  const float* Wk = (const float*)d_in[2];
  const float* Wv = (const float*)d_in[3];
  const float* Wo = (const float*)d_in[4];
  float* OUT = (float*)d_out;

  char* ws = (char*)d_ws;
  const size_t SZ_X  = (size_t)NB * T_SEQ * DM * 2;   // 16.78 MB
  const size_t SZ_W  = (size_t)DM * DM * 2;           // 2.10 MB
  const size_t SZ_QK = (size_t)NB * T_SEQ * QKS * 2;  // 33.55 MB
  __bf16* Xb  = (__bf16*)ws; ws += SZ_X;
  __bf16* Wqb = (__bf16*)ws; ws += SZ_W;   // Wqb and Wkb contiguous ->
  __bf16* Wkb = (__bf16*)ws; ws += SZ_W;   // fused [Wq;Wk] of 2048x1024
  __bf16* Wvb = (__bf16*)ws; ws += SZ_W;
  __bf16* Wob = (__bf16*)ws; ws += SZ_W;
  __bf16* QKb = (__bf16*)ws; ws += SZ_QK;
  __bf16* VTb = (__bf16*)ws; ws += SZ_X;
  __bf16* AOb = (__bf16*)ws; ws += SZ_X;

  const int M = NB * T_SEQ;  // 8192

  cast_f32_to_bf16<<<(M * DM / 4) / 256, 256, 0, stream>>>(X, Xb, M * DM / 4);
  cast_weights<<<dim3(DM * DM / 4 / 256, 4), 256, 0, stream>>>(Wq, Wk, Wv, Wo,
                                                               Wqb, Wkb, Wvb, Wob);

  // [Q|K] = X @ [Wq;Wk]^T, Q cols pre-scaled by 0.125*log2e
  gemm_nt<__bf16, 1><<<dim3(QKS / 128, M / 128), 256, 0, stream>>>(Xb, Wqb, QKb, M, QKS, DM);
  // VT[d][key'] = sigma-permuted V^T  (V = X @ Wv^T)
  gemm_nt<__bf16, 2><<<dim3(M / 128, DM / 128), 256, 0, stream>>>(Wvb, Xb, VTb, DM, M, DM);
  // attention (512 blocks, quad-chunk)
  attn_fwd<<<dim3(8, NB * NH), 256, 0, stream>>>(QKb, VTb, AOb);
  // OUT = AO @ Wo^T (fp32 out)
  gemm_nt<float, 0><<<dim3(DM / 128, M / 128), 256, 0, stream>>>(AOb, Wob, OUT, M, DM, DM);
}

// Round 11
// 146.370 us; speedup vs baseline: 1.2958x; 1.1104x over previous
//
#include <hip/hip_runtime.h>
#include <hip/hip_bf16.h>

#define T_SEQ 2048
#define NB 4
#define NH 16
#define DK 64
#define DM 1024
#define QKS 2048  // row stride of fused [Q|K] buffer

typedef __attribute__((ext_vector_type(8))) __bf16 bf16x8;
typedef __attribute__((ext_vector_type(4))) __bf16 bf16x4;
typedef __attribute__((ext_vector_type(4))) float f32x4;
typedef __attribute__((ext_vector_type(2))) int i32x2;
typedef __attribute__((ext_vector_type(4))) int i32x4;

// async global->LDS, 16B per lane, wave-uniform LDS base + lane*16
__device__ __forceinline__ void gl_lds16(const __bf16* g, __bf16* l) {
  __builtin_amdgcn_global_load_lds(
      (const __attribute__((address_space(1))) void*)g,
      (__attribute__((address_space(3))) void*)l,
      16, 0, 0);
}

__device__ __forceinline__ unsigned cvt_pk_bf16(float lo, float hi) {
  unsigned r;
  asm("v_cvt_pk_bf16_f32 %0, %1, %2" : "=v"(r) : "v"(lo), "v"(hi));
  return r;
}

// ---------------- cast fp32 -> bf16, vectorized ----------------
__global__ __launch_bounds__(256) void cast_f32_to_bf16(const float* __restrict__ in,
                                                        __bf16* __restrict__ out, int n4) {
  int i = blockIdx.x * 256 + threadIdx.x;
  if (i >= n4) return;
  float4 v = reinterpret_cast<const float4*>(in)[i];
  bf16x4 o;
  o[0] = (__bf16)v.x; o[1] = (__bf16)v.y; o[2] = (__bf16)v.z; o[3] = (__bf16)v.w;
  reinterpret_cast<bf16x4*>(out)[i] = o;
}

// fused cast of the four weight matrices (each DM*DM fp32)
__global__ __launch_bounds__(256) void cast_weights(const float* __restrict__ a,
                                                    const float* __restrict__ b,
                                                    const float* __restrict__ c,
                                                    const float* __restrict__ d,
                                                    __bf16* __restrict__ oa,
                                                    __bf16* __restrict__ ob,
                                                    __bf16* __restrict__ oc,
                                                    __bf16* __restrict__ od) {
  const int which = blockIdx.y;
  const float* in = (which == 0) ? a : (which == 1) ? b : (which == 2) ? c : d;
  __bf16* out = (which == 0) ? oa : (which == 1) ? ob : (which == 2) ? oc : od;
  int i = blockIdx.x * 256 + threadIdx.x;
  float4 v = reinterpret_cast<const float4*>(in)[i];
  bf16x4 o;
  o[0] = (__bf16)v.x; o[1] = (__bf16)v.y; o[2] = (__bf16)v.z; o[3] = (__bf16)v.w;
  reinterpret_cast<bf16x4*>(out)[i] = o;
}

// ---------------- NT GEMM (m97-style): C[M,N] = A[M,K] * B[N,K]^T ---------
// MODE 0: plain.  MODE 1: scale cols <1024 by 0.125*log2e (fused QK).
// MODE 2: sigma-permute N within 32-groups (VT for attn PV fragments).
template<typename CT, int MODE>
__global__ __launch_bounds__(256, 2) void gemm_nt(const __bf16* __restrict__ A,
                                                  const __bf16* __restrict__ B,
                                                  CT* __restrict__ C,
                                                  int M, int N, int K) {
  __shared__ alignas(16) __bf16 As[128][64];
  __shared__ alignas(16) __bf16 Bs[128][64];
  const int tid = threadIdx.x;
  const int m0 = blockIdx.y * 128, n0 = blockIdx.x * 128;
  const int w = tid >> 6, l = tid & 63, lg = l >> 4, lr = l & 15;
  const int wr = (w >> 1) * 64, wc = (w & 1) * 64;
  const int srow = l >> 3;              // 0..7 within 8-row segment
  const int schunk = (l & 7) ^ srow;    // inverse-swizzled source 16B chunk

  f32x4 acc[4][4] = {};
  const int rsw = lr & 7;

  for (int k0 = 0; k0 < K; k0 += 64) {
    __syncthreads();
    #pragma unroll
    for (int j = 0; j < 4; ++j) {
      const int rbase = (w * 4 + j) * 8;
      gl_lds16(A + (size_t)(m0 + rbase + srow) * K + k0 + schunk * 8, &As[rbase][0]);
      gl_lds16(B + (size_t)(n0 + rbase + srow) * K + k0 + schunk * 8, &Bs[rbase][0]);
    }
    asm volatile("s_waitcnt vmcnt(0)" ::: "memory");
    __syncthreads();
    #pragma unroll
    for (int kk = 0; kk < 2; ++kk) {
      bf16x8 af[4], bfr[4];
      #pragma unroll
      for (int mt = 0; mt < 4; ++mt) {
        const char* p = (const char*)&As[wr + mt * 16 + lr][0];
        af[mt] = *reinterpret_cast<const bf16x8*>(p + (((kk * 4 + lg) ^ rsw) << 4));
      }
      #pragma unroll
      for (int nt = 0; nt < 4; ++nt) {
        const char* p = (const char*)&Bs[wc + nt * 16 + lr][0];
        bfr[nt] = *reinterpret_cast<const bf16x8*>(p + (((kk * 4 + lg) ^ rsw) << 4));
      }
      __builtin_amdgcn_s_setprio(1);
      #pragma unroll
      for (int mt = 0; mt < 4; ++mt)
        #pragma unroll
        for (int nt = 0; nt < 4; ++nt)
          acc[mt][nt] = __builtin_amdgcn_mfma_f32_16x16x32_bf16(af[mt], bfr[nt], acc[mt][nt], 0, 0, 0);
      __builtin_amdgcn_s_setprio(0);
    }
  }
  const float qsc = (MODE == 1 && n0 < 1024) ? 0.18033688f : 1.0f;
  #pragma unroll
  for (int mt = 0; mt < 4; ++mt)
    #pragma unroll
    for (int nt = 0; nt < 4; ++nt)
      #pragma unroll
      for (int r = 0; r < 4; ++r) {
        const int mg = m0 + wr + mt * 16 + 4 * lg + r;
        int ng = n0 + wc + nt * 16 + lr;
        if (MODE == 2)  // sigma^-1 within 32-key group: key kappa -> slot
          ng = (ng & ~31) | (8 * (lr >> 2) + (lr & 3) + ((nt & 1) << 2));
        float v = acc[mt][nt][r];
        if (MODE == 1) v *= qsc;
        C[(size_t)mg * N + ng] = (CT)v;
      }
}

// ---------------- causal flash attention ----------------------------------
// grid: 512 blocks (8 per bh); XCD remap: bh = (f&7)*8|(f>>3)&7, c = f>>6.
// QUAD-chunk merge; no-max softmax with RAW v_exp_f32; swapped QK^T;
// sigma-permuted VT; l-sum via ones-column MFMA (no shuffles at all).
__global__ __launch_bounds__(256, 2) void attn_fwd(const __bf16* __restrict__ QK,
                                                   const __bf16* __restrict__ VT,
                                                   __bf16* __restrict__ AO) {
  __shared__ alignas(16) __bf16 Ks[2][64][64];
  __shared__ alignas(16) __bf16 Vs[2][64][64];  // sigma-permuted V^T tile
  const int tid = threadIdx.x;
  const int w = tid >> 6, l = tid & 63, lg = l >> 4, lr = l & 15;

  const int fl = (int)blockIdx.x + 8 * (int)blockIdx.y;  // dispatch order
  const int bh = ((fl & 7) << 3) | ((fl >> 3) & 7);
  const int c = fl >> 6;  // 0..7
  const int b = bh >> 4, h = bh & 15;
  const size_t bT = (size_t)b * T_SEQ;
  const int M = NB * T_SEQ;

  const int srow = l >> 3;
  const int schunk = (l & 7) ^ srow;  // inverse-swizzled source chunk
  const __bf16* Kg = QK + bT * QKS + 1024 + h * DK;   // K half of fused buffer
  const __bf16* Vg = VT + (size_t)(h * DK) * M + bT;
  const int rsw = lr & 7;

  // ones B-fragment for the l-sum MFMA (sum_k P[q][k] * 1)
  bf16x8 vone;
  #pragma unroll
  for (int j = 0; j < 8; ++j) vone[j] = (__bf16)1.0f;

  // chunk q-block indices (64-row chunks), nested activity A<=B<=C<=D
  const int qbA = c, qbB = 15 - c, qbC = 16 + c, qbD = 31 - c;
  const int qrwA = qbA * 64 + w * 16, qrwB = qbB * 64 + w * 16;
  const int qrwC = qbC * 64 + w * 16, qrwD = qbD * 64 + w * 16;
  const int klA = qbA * 64, klB = qbB * 64, klC = qbC * 64, klD = qbD * 64;

  const __bf16* QpA = QK + (bT + qrwA + lr) * QKS + h * DK;
  const __bf16* QpB = QK + (bT + qrwB + lr) * QKS + h * DK;
  const __bf16* QpC = QK + (bT + qrwC + lr) * QKS + h * DK;
  const __bf16* QpD = QK + (bT + qrwD + lr) * QKS + h * DK;
  const bf16x8 qfA0 = *reinterpret_cast<const bf16x8*>(QpA + 8 * lg);
  const bf16x8 qfA1 = *reinterpret_cast<const bf16x8*>(QpA + 32 + 8 * lg);
  const bf16x8 qfB0 = *reinterpret_cast<const bf16x8*>(QpB + 8 * lg);
  const bf16x8 qfB1 = *reinterpret_cast<const bf16x8*>(QpB + 32 + 8 * lg);
  const bf16x8 qfC0 = *reinterpret_cast<const bf16x8*>(QpC + 8 * lg);
  const bf16x8 qfC1 = *reinterpret_cast<const bf16x8*>(QpC + 32 + 8 * lg);
  const bf16x8 qfD0 = *reinterpret_cast<const bf16x8*>(QpD + 8 * lg);
  const bf16x8 qfD1 = *reinterpret_cast<const bf16x8*>(QpD + 32 + 8 * lg);

  f32x4 o_accA[4] = {}, o_accB[4] = {}, o_accC[4] = {}, o_accD[4] = {};
  f32x4 lA = {}, lB = {}, lC = {}, lD = {};

  auto STAGE = [&](int buf, int kbase) {
    #pragma unroll
    for (int i = 0; i < 2; ++i) {
      const int seg = w * 2 + i;
      gl_lds16(Kg + (size_t)(kbase + seg * 8 + srow) * QKS + schunk * 8,
               &Ks[buf][seg * 8][0]);
      gl_lds16(Vg + (size_t)(seg * 8 + srow) * M + kbase + schunk * 8,
               &Vs[buf][seg * 8][0]);
    }
  };

  // one chunk's tile: swapped QK^T -> P in-register -> PV + l via ones-MFMA
  auto CHUNK = [&](const bf16x8& qf0, const bf16x8& qf1, f32x4* o_acc,
                   f32x4& l_acc, int qrw, bool masked, int k0,
                   const bf16x8* kf, const bf16x8* vf) {
    f32x4 s[4] = {};
    __builtin_amdgcn_s_setprio(1);
    #pragma unroll
    for (int ct = 0; ct < 4; ++ct) {
      s[ct] = __builtin_amdgcn_mfma_f32_16x16x32_bf16(kf[2 * ct], qf0, s[ct], 0, 0, 0);
      s[ct] = __builtin_amdgcn_mfma_f32_16x16x32_bf16(kf[2 * ct + 1], qf1, s[ct], 0, 0, 0);
    }
    __builtin_amdgcn_s_setprio(0);
    if (masked) {  // causal: lane holds q=lr, key=k0+16ct+4lg+r
      #pragma unroll
      for (int ct = 0; ct < 4; ++ct)
        #pragma unroll
        for (int r = 0; r < 4; ++r)
          if (k0 + 16 * ct + 4 * lg + r > qrw + lr) s[ct][r] = -1e30f;
    }
    // P = 2^S (raw v_exp_f32: bounded S; -1e30 -> 0); pack to A-fragments
    unsigned pk[4][2];
    #pragma unroll
    for (int ct = 0; ct < 4; ++ct) {
      const float p0 = __builtin_amdgcn_exp2f(s[ct][0]);
      const float p1 = __builtin_amdgcn_exp2f(s[ct][1]);
      const float p2 = __builtin_amdgcn_exp2f(s[ct][2]);
      const float p3 = __builtin_amdgcn_exp2f(s[ct][3]);
      pk[ct][0] = cvt_pk_bf16(p0, p1);
      pk[ct][1] = cvt_pk_bf16(p2, p3);
    }
    const bf16x8 pf0 = __builtin_bit_cast(bf16x8, i32x4{(int)pk[0][0], (int)pk[0][1],
                                                        (int)pk[1][0], (int)pk[1][1]});
    const bf16x8 pf1 = __builtin_bit_cast(bf16x8, i32x4{(int)pk[2][0], (int)pk[2][1],
                                                        (int)pk[3][0], (int)pk[3][1]});
    __builtin_amdgcn_s_setprio(1);
    l_acc = __builtin_amdgcn_mfma_f32_16x16x32_bf16(pf0, vone, l_acc, 0, 0, 0);
    l_acc = __builtin_amdgcn_mfma_f32_16x16x32_bf16(pf1, vone, l_acc, 0, 0, 0);
    #pragma unroll
    for (int dt = 0; dt < 4; ++dt) {
      o_acc[dt] = __builtin_amdgcn_mfma_f32_16x16x32_bf16(pf0, vf[2 * dt],     o_acc[dt], 0, 0, 0);
      o_acc[dt] = __builtin_amdgcn_mfma_f32_16x16x32_bf16(pf1, vf[2 * dt + 1], o_acc[dt], 0, 0, 0);
    }
    __builtin_amdgcn_s_setprio(0);
  };

  STAGE(0, 0);
  asm volatile("s_waitcnt vmcnt(0)" ::: "memory");
  __syncthreads();
  int buf = 0;

  for (int k0 = 0; k0 <= klD; k0 += 64) {
    if (k0 + 64 <= klD) STAGE(buf ^ 1, k0 + 64);

    // K and V fragments from LDS (swizzled b128) -- shared by all 4 chunks
    bf16x8 kf[8], vf[8];
    #pragma unroll
    for (int ct = 0; ct < 4; ++ct) {
      const char* kb = (const char*)&Ks[buf][ct * 16 + lr][0];
      kf[2 * ct]     = *reinterpret_cast<const bf16x8*>(kb + ((lg ^ rsw) << 4));
      kf[2 * ct + 1] = *reinterpret_cast<const bf16x8*>(kb + (((lg + 4) ^ rsw) << 4));
      const char* vb = (const char*)&Vs[buf][ct * 16 + lr][0];
      vf[2 * ct]     = *reinterpret_cast<const bf16x8*>(vb + ((lg ^ rsw) << 4));
      vf[2 * ct + 1] = *reinterpret_cast<const bf16x8*>(vb + (((lg + 4) ^ rsw) << 4));
    }

    CHUNK(qfD0, qfD1, o_accD, lD, qrwD, k0 == klD, k0, kf, vf);
    if (k0 <= klC) CHUNK(qfC0, qfC1, o_accC, lC, qrwC, k0 == klC, k0, kf, vf);
    if (k0 <= klB) CHUNK(qfB0, qfB1, o_accB, lB, qrwB, k0 == klB, k0, kf, vf);
    if (k0 <= klA) CHUNK(qfA0, qfA1, o_accA, lA, qrwA, k0 == klA, k0, kf, vf);

    asm volatile("s_waitcnt vmcnt(0)" ::: "memory");
    __syncthreads();
    buf ^= 1;
  }

  // --- output: l_acc rows align with o_acc rows (q = 4lg+r); no shuffles ---
  #pragma unroll
  for (int cc = 0; cc < 4; ++cc) {
    const f32x4& la = (cc == 0) ? lA : (cc == 1) ? lB : (cc == 2) ? lC : lD;
    f32x4* oa = (cc == 0) ? o_accA : (cc == 1) ? o_accB : (cc == 2) ? o_accC : o_accD;
    const int qrw = (cc == 0) ? qrwA : (cc == 1) ? qrwB : (cc == 2) ? qrwC : qrwD;
    #pragma unroll
    for (int r = 0; r < 4; ++r) {
      const float inv = 1.0f / la[r];
      #pragma unroll
      for (int dt = 0; dt < 4; ++dt) {
        const int rg = qrw + 4 * lg + r;
        const int cg = h * DK + dt * 16 + lr;
        AO[(bT + rg) * DM + cg] = (__bf16)(oa[dt][r] * inv);
      }
    }
  }
}

extern "C" void kernel_launch(void* const* d_in, const int* in_sizes, int n_in,
                              void* d_out, int out_size, void* d_ws, size_t ws_size,
                              hipStream_t stream) {
  (void)in_sizes; (void)n_in; (void)out_size; (void)ws_size;
  const float* X  = (const float*)d_in[0];
  const float* Wq = (const float*)d_in[1];
  const float* Wk = (const float*)d_in[2];
  const float* Wv = (const float*)d_in[3];
  const float* Wo = (const float*)d_in[4];
  float* OUT = (float*)d_out;

  char* ws = (char*)d_ws;
  const size_t SZ_X  = (size_t)NB * T_SEQ * DM * 2;   // 16.78 MB
  const size_t SZ_W  = (size_t)DM * DM * 2;           // 2.10 MB
  const size_t SZ_QK = (size_t)NB * T_SEQ * QKS * 2;  // 33.55 MB
  __bf16* Xb  = (__bf16*)ws; ws += SZ_X;
  __bf16* Wqb = (__bf16*)ws; ws += SZ_W;   // Wqb and Wkb contiguous ->
  __bf16* Wkb = (__bf16*)ws; ws += SZ_W;   // fused [Wq;Wk] of 2048x1024
  __bf16* Wvb = (__bf16*)ws; ws += SZ_W;
  __bf16* Wob = (__bf16*)ws; ws += SZ_W;
  __bf16* QKb = (__bf16*)ws; ws += SZ_QK;
  __bf16* VTb = (__bf16*)ws; ws += SZ_X;
  __bf16* AOb = (__bf16*)ws; ws += SZ_X;

  const int M = NB * T_SEQ;  // 8192

  cast_f32_to_bf16<<<(M * DM / 4) / 256, 256, 0, stream>>>(X, Xb, M * DM / 4);
  cast_weights<<<dim3(DM * DM / 4 / 256, 4), 256, 0, stream>>>(Wq, Wk, Wv, Wo,
                                                               Wqb, Wkb, Wvb, Wob);

  // [Q|K] = X @ [Wq;Wk]^T, Q cols pre-scaled by 0.125*log2e
  gemm_nt<__bf16, 1><<<dim3(QKS / 128, M / 128), 256, 0, stream>>>(Xb, Wqb, QKb, M, QKS, DM);
  // VT[d][key'] = sigma-permuted V^T  (V = X @ Wv^T)
  gemm_nt<__bf16, 2><<<dim3(M / 128, DM / 128), 256, 0, stream>>>(Wvb, Xb, VTb, DM, M, DM);
  // attention (512 blocks, quad-chunk)
  attn_fwd<<<dim3(8, NB * NH), 256, 0, stream>>>(QKb, VTb, AOb);
  // OUT = AO @ Wo^T (fp32 out)
  gemm_nt<float, 0><<<dim3(DM / 128, M / 128), 256, 0, stream>>>(AOb, Wob, OUT, M, DM, DM);
}

// Round 12
// 143.170 us; speedup vs baseline: 1.3248x; 1.0223x over previous
//
#include <hip/hip_runtime.h>
#include <hip/hip_bf16.h>

#define T_SEQ 2048
#define NB 4
#define NH 16
#define DK 64
#define DM 1024
#define QKS 2048  // row stride of fused [Q|K] buffer

typedef __attribute__((ext_vector_type(8))) __bf16 bf16x8;
typedef __attribute__((ext_vector_type(4))) __bf16 bf16x4;
typedef __attribute__((ext_vector_type(4))) float f32x4;
typedef __attribute__((ext_vector_type(2))) int i32x2;
typedef __attribute__((ext_vector_type(4))) int i32x4;

// async global->LDS, 16B per lane, wave-uniform LDS base + lane*16
__device__ __forceinline__ void gl_lds16(const __bf16* g, __bf16* l) {
  __builtin_amdgcn_global_load_lds(
      (const __attribute__((address_space(1))) void*)g,
      (__attribute__((address_space(3))) void*)l,
      16, 0, 0);
}

__device__ __forceinline__ unsigned cvt_pk_bf16(float lo, float hi) {
  unsigned r;
  asm("v_cvt_pk_bf16_f32 %0, %1, %2" : "=v"(r) : "v"(lo), "v"(hi));
  return r;
}

// ---------------- cast fp32 -> bf16, vectorized ----------------
__global__ __launch_bounds__(256) void cast_f32_to_bf16(const float* __restrict__ in,
                                                        __bf16* __restrict__ out, int n4) {
  int i = blockIdx.x * 256 + threadIdx.x;
  if (i >= n4) return;
  float4 v = reinterpret_cast<const float4*>(in)[i];
  bf16x4 o;
  o[0] = (__bf16)v.x; o[1] = (__bf16)v.y; o[2] = (__bf16)v.z; o[3] = (__bf16)v.w;
  reinterpret_cast<bf16x4*>(out)[i] = o;
}

// fused cast of the four weight matrices (each DM*DM fp32)
__global__ __launch_bounds__(256) void cast_weights(const float* __restrict__ a,
                                                    const float* __restrict__ b,
                                                    const float* __restrict__ c,
                                                    const float* __restrict__ d,
                                                    __bf16* __restrict__ oa,
                                                    __bf16* __restrict__ ob,
                                                    __bf16* __restrict__ oc,
                                                    __bf16* __restrict__ od) {
  const int which = blockIdx.y;
  const float* in = (which == 0) ? a : (which == 1) ? b : (which == 2) ? c : d;
  __bf16* out = (which == 0) ? oa : (which == 1) ? ob : (which == 2) ? oc : od;
  int i = blockIdx.x * 256 + threadIdx.x;
  float4 v = reinterpret_cast<const float4*>(in)[i];
  bf16x4 o;
  o[0] = (__bf16)v.x; o[1] = (__bf16)v.y; o[2] = (__bf16)v.z; o[3] = (__bf16)v.w;
  reinterpret_cast<bf16x4*>(out)[i] = o;
}

// ---------------- 256x256 8-phase GEMM (T3+T4+T5): C = A * B^T ------------
// 512 thr = 8 waves (2M x 4N), BK=64, 2 K-tiles/iter, counted vmcnt(6).
// Staging stagger: B halves at P2/P3 (freed after P1), A halves at P4/P5
// (freed after P3); tile's last half issued 3 half-tiles (6 loads) before
// its consuming wait -> vmcnt(6) at P4 & P8. Raw s_barrier only.
template<int DO_QSCALE>
__global__ __launch_bounds__(512, 2) void gemm_nt_8p(const __bf16* __restrict__ A,
                                                     const __bf16* __restrict__ Bm,
                                                     __bf16* __restrict__ C,
                                                     int M, int N, int K) {
  __shared__ alignas(16) __bf16 As[2][256][64];
  __shared__ alignas(16) __bf16 Bs[2][256][64];
  const int tid = threadIdx.x;
  const int wid = tid >> 6, l = tid & 63, lg = l >> 4, lr = l & 15;
  const int wm = wid >> 2, wn = wid & 3;
  // bijective XCD swizzle (gridDim.x % 8 == 0)
  const int f = (int)blockIdx.x;
  const int cpx = (int)gridDim.x >> 3;
  const int swz = (f & 7) * cpx + (f >> 3);
  const int nbn = N >> 8;
  const int m0 = (swz / nbn) << 8, n0 = (swz % nbn) << 8;

  const int srow = l >> 3;
  const int schunk = (l & 7) ^ srow;  // inverse-swizzled source chunk
  const int rsw = lr & 7;
  const int strow = wid * 8 + srow;   // staging row within a 64-row group

  f32x4 acc[8][4] = {};
  bf16x8 aA[8], bB[8];

  auto SA = [&](int buf, int half, int t) {
    #pragma unroll
    for (int j = 0; j < 2; ++j)
      gl_lds16(A + (size_t)(m0 + half * 128 + j * 64 + strow) * K + t * 64 + schunk * 8,
               &As[buf][half * 128 + j * 64 + wid * 8][0]);
  };
  auto SB = [&](int buf, int half, int t) {
    #pragma unroll
    for (int j = 0; j < 2; ++j)
      gl_lds16(Bm + (size_t)(n0 + half * 128 + j * 64 + strow) * K + t * 64 + schunk * 8,
               &Bs[buf][half * 128 + j * 64 + wid * 8][0]);
  };
  auto LA = [&](int buf, int mh) {
    #pragma unroll
    for (int mt = 0; mt < 4; ++mt) {
      const char* p = (const char*)&As[buf][wm * 128 + mh * 64 + mt * 16 + lr][0];
      aA[mt * 2 + 0] = *reinterpret_cast<const bf16x8*>(p + ((lg ^ rsw) << 4));
      aA[mt * 2 + 1] = *reinterpret_cast<const bf16x8*>(p + (((4 + lg) ^ rsw) << 4));
    }
  };
  auto LB = [&](int buf) {
    #pragma unroll
    for (int nt = 0; nt < 4; ++nt) {
      const char* p = (const char*)&Bs[buf][wn * 64 + nt * 16 + lr][0];
      bB[nt * 2 + 0] = *reinterpret_cast<const bf16x8*>(p + ((lg ^ rsw) << 4));
      bB[nt * 2 + 1] = *reinterpret_cast<const bf16x8*>(p + (((4 + lg) ^ rsw) << 4));
    }
  };
  auto MQ = [&](int mh, int nh) {
    #pragma unroll
    for (int mt = 0; mt < 4; ++mt)
      #pragma unroll
      for (int ntl = 0; ntl < 2; ++ntl) {
        const int nt = nh * 2 + ntl;
        acc[mh * 4 + mt][nt] = __builtin_amdgcn_mfma_f32_16x16x32_bf16(
            aA[mt * 2 + 0], bB[nt * 2 + 0], acc[mh * 4 + mt][nt], 0, 0, 0);
        acc[mh * 4 + mt][nt] = __builtin_amdgcn_mfma_f32_16x16x32_bf16(
            aA[mt * 2 + 1], bB[nt * 2 + 1], acc[mh * 4 + mt][nt], 0, 0, 0);
      }
  };

  // prologue: tile0 fully + tile1's B halves and A-half0 (7 half-tiles)
  SB(0, 0, 0); SB(0, 1, 0); SA(0, 0, 0); SA(0, 1, 0);
  SB(1, 0, 1); SB(1, 1, 1); SA(1, 0, 1);
  asm volatile("s_waitcnt vmcnt(6)" ::: "memory");  // tile0's 8 loads landed
  __builtin_amdgcn_s_barrier();

  const int NIT = K >> 7;
  for (int i = 0; i < NIT; ++i) {
    const bool lastit = (i == NIT - 1);
    const int t2 = 2 * i + 2, t3 = 2 * i + 3;
    // P1: read buf0 A-mh0 + all B; stage t(2i+1).Ah1
    LA(0, 0); LB(0);
    SA(1, 1, 2 * i + 1);
    __builtin_amdgcn_s_barrier();
    asm volatile("s_waitcnt lgkmcnt(0)" ::: "memory");
    __builtin_amdgcn_sched_barrier(0);
    __builtin_amdgcn_s_setprio(1); MQ(0, 0); __builtin_amdgcn_s_setprio(0);
    __builtin_amdgcn_s_barrier();
    // P2: stage t+2.Bh0 (buf0 B freed after P1)
    if (!lastit) SB(0, 0, t2);
    __builtin_amdgcn_s_setprio(1); MQ(0, 1); __builtin_amdgcn_s_setprio(0);
    __builtin_amdgcn_s_barrier();
    // P3: read buf0 A-mh1; stage t+2.Bh1
    LA(0, 1);
    if (!lastit) SB(0, 1, t2);
    __builtin_amdgcn_s_barrier();
    asm volatile("s_waitcnt lgkmcnt(0)" ::: "memory");
    __builtin_amdgcn_sched_barrier(0);
    __builtin_amdgcn_s_setprio(1); MQ(1, 1); __builtin_amdgcn_s_setprio(0);
    __builtin_amdgcn_s_barrier();
    // P4: stage t+2.Ah0 (buf0 A freed after P3); wait tile 2i+1 landed
    if (!lastit) SA(0, 0, t2);
    __builtin_amdgcn_s_setprio(1); MQ(1, 0); __builtin_amdgcn_s_setprio(0);
    if (lastit) asm volatile("s_waitcnt vmcnt(0)" ::: "memory");
    else        asm volatile("s_waitcnt vmcnt(6)" ::: "memory");
    __builtin_amdgcn_s_barrier();
    // P5: read buf1 A-mh0 + all B; stage t+2.Ah1
    LA(1, 0); LB(1);
    if (!lastit) SA(0, 1, t2);
    __builtin_amdgcn_s_barrier();
    asm volatile("s_waitcnt lgkmcnt(0)" ::: "memory");
    __builtin_amdgcn_sched_barrier(0);
    __builtin_amdgcn_s_setprio(1); MQ(0, 0); __builtin_amdgcn_s_setprio(0);
    __builtin_amdgcn_s_barrier();
    // P6: stage t+3.Bh0 (buf1 B freed after P5)
    if (!lastit) SB(1, 0, t3);
    __builtin_amdgcn_s_setprio(1); MQ(0, 1); __builtin_amdgcn_s_setprio(0);
    __builtin_amdgcn_s_barrier();
    // P7: read buf1 A-mh1; stage t+3.Bh1
    LA(1, 1);
    if (!lastit) SB(1, 1, t3);
    __builtin_amdgcn_s_barrier();
    asm volatile("s_waitcnt lgkmcnt(0)" ::: "memory");
    __builtin_amdgcn_sched_barrier(0);
    __builtin_amdgcn_s_setprio(1); MQ(1, 1); __builtin_amdgcn_s_setprio(0);
    __builtin_amdgcn_s_barrier();
    // P8: stage t+3.Ah0; wait tile 2i+2 landed (t+3.Ah1 slides to next P1)
    if (!lastit) SA(1, 0, t3);
    __builtin_amdgcn_s_setprio(1); MQ(1, 0); __builtin_amdgcn_s_setprio(0);
    if (!lastit) asm volatile("s_waitcnt vmcnt(6)" ::: "memory");
    __builtin_amdgcn_s_barrier();
  }

  // epilogue
  #pragma unroll
  for (int mt = 0; mt < 8; ++mt)
    #pragma unroll
    for (int nt = 0; nt < 4; ++nt) {
      const int ng = n0 + wn * 64 + nt * 16 + lr;
      const float sc = (DO_QSCALE && ng < 1024) ? 0.18033688f : 1.0f;
      #pragma unroll
      for (int r = 0; r < 4; ++r) {
        const int mg = m0 + wm * 128 + mt * 16 + 4 * lg + r;
        C[(size_t)mg * N + ng] = (__bf16)(acc[mt][nt][r] * sc);
      }
    }
}

// ---------------- NT GEMM (m97-style, 128^2): C[M,N] = A[M,K] * B[N,K]^T --
// MODE 0: plain.  MODE 2: sigma-permute N within 32-groups (VT).
template<typename CT, int MODE>
__global__ __launch_bounds__(256, 2) void gemm_nt(const __bf16* __restrict__ A,
                                                  const __bf16* __restrict__ B,
                                                  CT* __restrict__ C,
                                                  int M, int N, int K) {
  __shared__ alignas(16) __bf16 As[128][64];
  __shared__ alignas(16) __bf16 Bs[128][64];
  const int tid = threadIdx.x;
  const int m0 = blockIdx.y * 128, n0 = blockIdx.x * 128;
  const int w = tid >> 6, l = tid & 63, lg = l >> 4, lr = l & 15;
  const int wr = (w >> 1) * 64, wc = (w & 1) * 64;
  const int srow = l >> 3;              // 0..7 within 8-row segment
  const int schunk = (l & 7) ^ srow;    // inverse-swizzled source 16B chunk

  f32x4 acc[4][4] = {};
  const int rsw = lr & 7;

  for (int k0 = 0; k0 < K; k0 += 64) {
    __syncthreads();
    #pragma unroll
    for (int j = 0; j < 4; ++j) {
      const int rbase = (w * 4 + j) * 8;
      gl_lds16(A + (size_t)(m0 + rbase + srow) * K + k0 + schunk * 8, &As[rbase][0]);
      gl_lds16(B + (size_t)(n0 + rbase + srow) * K + k0 + schunk * 8, &Bs[rbase][0]);
    }
    asm volatile("s_waitcnt vmcnt(0)" ::: "memory");
    __syncthreads();
    #pragma unroll
    for (int kk = 0; kk < 2; ++kk) {
      bf16x8 af[4], bfr[4];
      #pragma unroll
      for (int mt = 0; mt < 4; ++mt) {
        const char* p = (const char*)&As[wr + mt * 16 + lr][0];
        af[mt] = *reinterpret_cast<const bf16x8*>(p + (((kk * 4 + lg) ^ rsw) << 4));
      }
      #pragma unroll
      for (int nt = 0; nt < 4; ++nt) {
        const char* p = (const char*)&Bs[wc + nt * 16 + lr][0];
        bfr[nt] = *reinterpret_cast<const bf16x8*>(p + (((kk * 4 + lg) ^ rsw) << 4));
      }
      __builtin_amdgcn_s_setprio(1);
      #pragma unroll
      for (int mt = 0; mt < 4; ++mt)
        #pragma unroll
        for (int nt = 0; nt < 4; ++nt)
          acc[mt][nt] = __builtin_amdgcn_mfma_f32_16x16x32_bf16(af[mt], bfr[nt], acc[mt][nt], 0, 0, 0);
      __builtin_amdgcn_s_setprio(0);
    }
  }
  #pragma unroll
  for (int mt = 0; mt < 4; ++mt)
    #pragma unroll
    for (int nt = 0; nt < 4; ++nt)
      #pragma unroll
      for (int r = 0; r < 4; ++r) {
        const int mg = m0 + wr + mt * 16 + 4 * lg + r;
        int ng = n0 + wc + nt * 16 + lr;
        if (MODE == 2)  // sigma^-1 within 32-key group: key kappa -> slot
          ng = (ng & ~31) | (8 * (lr >> 2) + (lr & 3) + ((nt & 1) << 2));
        C[(size_t)mg * N + ng] = (CT)acc[mt][nt][r];
      }
}

// ---------------- causal flash attention ----------------------------------
// grid: 512 blocks (8 per bh); XCD remap: bh = (f&7)*8|(f>>3)&7, c = f>>6.
// QUAD-chunk merge; no-max softmax with RAW v_exp_f32; swapped QK^T;
// sigma-permuted VT; l-sum via ones-column MFMA (no shuffles at all).
__global__ __launch_bounds__(256, 2) void attn_fwd(const __bf16* __restrict__ QK,
                                                   const __bf16* __restrict__ VT,
                                                   __bf16* __restrict__ AO) {
  __shared__ alignas(16) __bf16 Ks[2][64][64];
  __shared__ alignas(16) __bf16 Vs[2][64][64];  // sigma-permuted V^T tile
  const int tid = threadIdx.x;
  const int w = tid >> 6, l = tid & 63, lg = l >> 4, lr = l & 15;

  const int fl = (int)blockIdx.x + 8 * (int)blockIdx.y;  // dispatch order
  const int bh = ((fl & 7) << 3) | ((fl >> 3) & 7);
  const int c = fl >> 6;  // 0..7
  const int b = bh >> 4, h = bh & 15;
  const size_t bT = (size_t)b * T_SEQ;
  const int M = NB * T_SEQ;

  const int srow = l >> 3;
  const int schunk = (l & 7) ^ srow;  // inverse-swizzled source chunk
  const __bf16* Kg = QK + bT * QKS + 1024 + h * DK;   // K half of fused buffer
  const __bf16* Vg = VT + (size_t)(h * DK) * M + bT;
  const int rsw = lr & 7;

  // ones B-fragment for the l-sum MFMA (sum_k P[q][k] * 1)
  bf16x8 vone;
  #pragma unroll
  for (int j = 0; j < 8; ++j) vone[j] = (__bf16)1.0f;

  // chunk q-block indices (64-row chunks), nested activity A<=B<=C<=D
  const int qbA = c, qbB = 15 - c, qbC = 16 + c, qbD = 31 - c;
  const int qrwA = qbA * 64 + w * 16, qrwB = qbB * 64 + w * 16;
  const int qrwC = qbC * 64 + w * 16, qrwD = qbD * 64 + w * 16;
  const int klA = qbA * 64, klB = qbB * 64, klC = qbC * 64, klD = qbD * 64;

  const __bf16* QpA = QK + (bT + qrwA + lr) * QKS + h * DK;
  const __bf16* QpB = QK + (bT + qrwB + lr) * QKS + h * DK;
  const __bf16* QpC = QK + (bT + qrwC + lr) * QKS + h * DK;
  const __bf16* QpD = QK + (bT + qrwD + lr) * QKS + h * DK;
  const bf16x8 qfA0 = *reinterpret_cast<const bf16x8*>(QpA + 8 * lg);
  const bf16x8 qfA1 = *reinterpret_cast<const bf16x8*>(QpA + 32 + 8 * lg);
  const bf16x8 qfB0 = *reinterpret_cast<const bf16x8*>(QpB + 8 * lg);
  const bf16x8 qfB1 = *reinterpret_cast<const bf16x8*>(QpB + 32 + 8 * lg);
  const bf16x8 qfC0 = *reinterpret_cast<const bf16x8*>(QpC + 8 * lg);
  const bf16x8 qfC1 = *reinterpret_cast<const bf16x8*>(QpC + 32 + 8 * lg);
  const bf16x8 qfD0 = *reinterpret_cast<const bf16x8*>(QpD + 8 * lg);
  const bf16x8 qfD1 = *reinterpret_cast<const bf16x8*>(QpD + 32 + 8 * lg);

  f32x4 o_accA[4] = {}, o_accB[4] = {}, o_accC[4] = {}, o_accD[4] = {};
  f32x4 lA = {}, lB = {}, lC = {}, lD = {};

  auto STAGE = [&](int buf, int kbase) {
    #pragma unroll
    for (int i = 0; i < 2; ++i) {
      const int seg = w * 2 + i;
      gl_lds16(Kg + (size_t)(kbase + seg * 8 + srow) * QKS + schunk * 8,
               &Ks[buf][seg * 8][0]);
      gl_lds16(Vg + (size_t)(seg * 8 + srow) * M + kbase + schunk * 8,
               &Vs[buf][seg * 8][0]);
    }
  };

  // one chunk's tile: swapped QK^T -> P in-register -> PV + l via ones-MFMA
  auto CHUNK = [&](const bf16x8& qf0, const bf16x8& qf1, f32x4* o_acc,
                   f32x4& l_acc, int qrw, bool masked, int k0,
                   const bf16x8* kf, const bf16x8* vf) {
    f32x4 s[4] = {};
    __builtin_amdgcn_s_setprio(1);
    #pragma unroll
    for (int ct = 0; ct < 4; ++ct) {
      s[ct] = __builtin_amdgcn_mfma_f32_16x16x32_bf16(kf[2 * ct], qf0, s[ct], 0, 0, 0);
      s[ct] = __builtin_amdgcn_mfma_f32_16x16x32_bf16(kf[2 * ct + 1], qf1, s[ct], 0, 0, 0);
    }
    __builtin_amdgcn_s_setprio(0);
    if (masked) {  // causal: lane holds q=lr, key=k0+16ct+4lg+r
      #pragma unroll
      for (int ct = 0; ct < 4; ++ct)
        #pragma unroll
        for (int r = 0; r < 4; ++r)
          if (k0 + 16 * ct + 4 * lg + r > qrw + lr) s[ct][r] = -1e30f;
    }
    // P = 2^S (raw v_exp_f32: bounded S; -1e30 -> 0); pack to A-fragments
    unsigned pk[4][2];
    #pragma unroll
    for (int ct = 0; ct < 4; ++ct) {
      const float p0 = __builtin_amdgcn_exp2f(s[ct][0]);
      const float p1 = __builtin_amdgcn_exp2f(s[ct][1]);
      const float p2 = __builtin_amdgcn_exp2f(s[ct][2]);
      const float p3 = __builtin_amdgcn_exp2f(s[ct][3]);
      pk[ct][0] = cvt_pk_bf16(p0, p1);
      pk[ct][1] = cvt_pk_bf16(p2, p3);
    }
    const bf16x8 pf0 = __builtin_bit_cast(bf16x8, i32x4{(int)pk[0][0], (int)pk[0][1],
                                                        (int)pk[1][0], (int)pk[1][1]});
    const bf16x8 pf1 = __builtin_bit_cast(bf16x8, i32x4{(int)pk[2][0], (int)pk[2][1],
                                                        (int)pk[3][0], (int)pk[3][1]});
    __builtin_amdgcn_s_setprio(1);
    l_acc = __builtin_amdgcn_mfma_f32_16x16x32_bf16(pf0, vone, l_acc, 0, 0, 0);
    l_acc = __builtin_amdgcn_mfma_f32_16x16x32_bf16(pf1, vone, l_acc, 0, 0, 0);
    #pragma unroll
    for (int dt = 0; dt < 4; ++dt) {
      o_acc[dt] = __builtin_amdgcn_mfma_f32_16x16x32_bf16(pf0, vf[2 * dt],     o_acc[dt], 0, 0, 0);
      o_acc[dt] = __builtin_amdgcn_mfma_f32_16x16x32_bf16(pf1, vf[2 * dt + 1], o_acc[dt], 0, 0, 0);
    }
    __builtin_amdgcn_s_setprio(0);
  };

  STAGE(0, 0);
  asm volatile("s_waitcnt vmcnt(0)" ::: "memory");
  __syncthreads();
  int buf = 0;

  for (int k0 = 0; k0 <= klD; k0 += 64) {
    if (k0 + 64 <= klD) STAGE(buf ^ 1, k0 + 64);

    // K and V fragments from LDS (swizzled b128) -- shared by all 4 chunks
    bf16x8 kf[8], vf[8];
    #pragma unroll
    for (int ct = 0; ct < 4; ++ct) {
      const char* kb = (const char*)&Ks[buf][ct * 16 + lr][0];
      kf[2 * ct]     = *reinterpret_cast<const bf16x8*>(kb + ((lg ^ rsw) << 4));
      kf[2 * ct + 1] = *reinterpret_cast<const bf16x8*>(kb + (((lg + 4) ^ rsw) << 4));
      const char* vb = (const char*)&Vs[buf][ct * 16 + lr][0];
      vf[2 * ct]     = *reinterpret_cast<const bf16x8*>(vb + ((lg ^ rsw) << 4));
      vf[2 * ct + 1] = *reinterpret_cast<const bf16x8*>(vb + (((lg + 4) ^ rsw) << 4));
    }

    CHUNK(qfD0, qfD1, o_accD, lD, qrwD, k0 == klD, k0, kf, vf);
    if (k0 <= klC) CHUNK(qfC0, qfC1, o_accC, lC, qrwC, k0 == klC, k0, kf, vf);
    if (k0 <= klB) CHUNK(qfB0, qfB1, o_accB, lB, qrwB, k0 == klB, k0, kf, vf);
    if (k0 <= klA) CHUNK(qfA0, qfA1, o_accA, lA, qrwA, k0 == klA, k0, kf, vf);

    asm volatile("s_waitcnt vmcnt(0)" ::: "memory");
    __syncthreads();
    buf ^= 1;
  }

  // --- output: l_acc rows align with o_acc rows (q = 4lg+r); no shuffles ---
  #pragma unroll
  for (int cc = 0; cc < 4; ++cc) {
    const f32x4& la = (cc == 0) ? lA : (cc == 1) ? lB : (cc == 2) ? lC : lD;
    f32x4* oa = (cc == 0) ? o_accA : (cc == 1) ? o_accB : (cc == 2) ? o_accC : o_accD;
    const int qrw = (cc == 0) ? qrwA : (cc == 1) ? qrwB : (cc == 2) ? qrwC : qrwD;
    #pragma unroll
    for (int r = 0; r < 4; ++r) {
      const float inv = 1.0f / la[r];
      #pragma unroll
      for (int dt = 0; dt < 4; ++dt) {
        const int rg = qrw + 4 * lg + r;
        const int cg = h * DK + dt * 16 + lr;
        AO[(bT + rg) * DM + cg] = (__bf16)(oa[dt][r] * inv);
      }
    }
  }
}

extern "C" void kernel_launch(void* const* d_in, const int* in_sizes, int n_in,
                              void* d_out, int out_size, void* d_ws, size_t ws_size,
                              hipStream_t stream) {
  (void)in_sizes; (void)n_in; (void)out_size; (void)ws_size;
  const float* X  = (const float*)d_in[0];
  const float* Wq = (const float*)d_in[1];
  const float* Wk = (const float*)d_in[2];
  const float* Wv = (const float*)d_in[3];
  const float* Wo = (const float*)d_in[4];
  float* OUT = (float*)d_out;

  char* ws = (char*)d_ws;
  const size_t SZ_X  = (size_t)NB * T_SEQ * DM * 2;   // 16.78 MB
  const size_t SZ_W  = (size_t)DM * DM * 2;           // 2.10 MB
  const size_t SZ_QK = (size_t)NB * T_SEQ * QKS * 2;  // 33.55 MB
  __bf16* Xb  = (__bf16*)ws; ws += SZ_X;
  __bf16* Wqb = (__bf16*)ws; ws += SZ_W;   // Wqb and Wkb contiguous ->
  __bf16* Wkb = (__bf16*)ws; ws += SZ_W;   // fused [Wq;Wk] of 2048x1024
  __bf16* Wvb = (__bf16*)ws; ws += SZ_W;
  __bf16* Wob = (__bf16*)ws; ws += SZ_W;
  __bf16* QKb = (__bf16*)ws; ws += SZ_QK;
  __bf16* VTb = (__bf16*)ws; ws += SZ_X;
  __bf16* AOb = (__bf16*)ws; ws += SZ_X;

  const int M = NB * T_SEQ;  // 8192

  cast_f32_to_bf16<<<(M * DM / 4) / 256, 256, 0, stream>>>(X, Xb, M * DM / 4);
  cast_weights<<<dim3(DM * DM / 4 / 256, 4), 256, 0, stream>>>(Wq, Wk, Wv, Wo,
                                                               Wqb, Wkb, Wvb, Wob);

  // [Q|K] = X @ [Wq;Wk]^T via 256^2 8-phase; Q cols pre-scaled by 0.125*log2e
  gemm_nt_8p<1><<<(M / 256) * (QKS / 256), 512, 0, stream>>>(Xb, Wqb, QKb, M, QKS, DM);
  // VT[d][key'] = sigma-permuted V^T  (V = X @ Wv^T)
  gemm_nt<__bf16, 2><<<dim3(M / 128, DM / 128), 256, 0, stream>>>(Wvb, Xb, VTb, DM, M, DM);
  // attention (512 blocks, quad-chunk)
  attn_fwd<<<dim3(8, NB * NH), 256, 0, stream>>>(QKb, VTb, AOb);
  // OUT = AO @ Wo^T (fp32 out)
  gemm_nt<float, 0><<<dim3(DM / 128, M / 128), 256, 0, stream>>>(AOb, Wob, OUT, M, DM, DM);
}